// Round 6
// baseline (606.606 us; speedup 1.0000x reference)
//
#include <hip/hip_runtime.h>
#include <hip/hip_bf16.h>
#include <hip/hip_fp16.h>
#include <math.h>

// Problem constants
#define NB 32     // batch
#define NN 128    // sequence (= 16 x 8)
#define ND 512    // model dim
#define NDI 1024  // inner dim
#define NDS 16    // state dim
#define NDR 32    // dt rank

typedef __attribute__((ext_vector_type(8))) __bf16 bf16x8;
typedef __attribute__((ext_vector_type(4))) float f32x4;

typedef __attribute__((address_space(3))) void lds_void;
typedef const __attribute__((address_space(1))) void glob_void;

__device__ __forceinline__ void gload16(const void* g, void* l) {
    __builtin_amdgcn_global_load_lds((glob_void*)g, (lds_void*)l, 16, 0, 0);
}

__device__ __forceinline__ unsigned short f2bf(float x) {
    __hip_bfloat16 h = __float2bfloat16(x);
    return *(unsigned short*)&h;
}

// full-rate DPP pair-sum: adds value from the xor-1 lane (quad_perm [1,0,3,2])
__device__ __forceinline__ float pair_sum(float y) {
    const int sw = __builtin_amdgcn_mov_dpp(__float_as_int(y), 0xB1, 0xF, 0xF, true);
    return y + __int_as_float(sw);
}

// ---------------------------------------------------------------------------
// K0: fp32 -> bf16 conversion (RTNE). k_cvt3 handles r,n,t in one launch.
// ---------------------------------------------------------------------------
__global__ __launch_bounds__(256) void k_cvt(
    const float* __restrict__ s, unsigned short* __restrict__ d, int n4)
{
    for (int i = blockIdx.x * 256 + threadIdx.x; i < n4; i += gridDim.x * 256) {
        const float4 v = ((const float4*)s)[i];
        ushort4 o;
        o.x = f2bf(v.x); o.y = f2bf(v.y); o.z = f2bf(v.z); o.w = f2bf(v.w);
        ((ushort4*)d)[i] = o;
    }
}

__global__ __launch_bounds__(256) void k_cvt3(
    const float* __restrict__ rr, const float* __restrict__ nn,
    const float* __restrict__ tt, unsigned short* __restrict__ d, int n4)
{
    const int z = blockIdx.z;
    const float* __restrict__ s = (z == 0) ? rr : (z == 1) ? nn : tt;
    unsigned short* __restrict__ dz = d + (size_t)z * n4 * 4;
    for (int i = blockIdx.x * 256 + threadIdx.x; i < n4; i += gridDim.x * 256) {
        const float4 v = ((const float4*)s)[i];
        ushort4 o;
        o.x = f2bf(v.x); o.y = f2bf(v.y); o.z = f2bf(v.z); o.w = f2bf(v.w);
        ((ushort4*)dz)[i] = o;
    }
}

// ---------------------------------------------------------------------------
// K1: in_proj as bf16 MFMA GEMM (m97 structure). Tile 128x128, BK=32.
// ---------------------------------------------------------------------------
__global__ __launch_bounds__(256) void k_gemm_inproj(
    const unsigned short* __restrict__ Abf,
    const unsigned short* __restrict__ Wbf,
    float* __restrict__ xb, __hip_bfloat16* __restrict__ zbf)
{
    const int m = blockIdx.z;
    const int row0 = blockIdx.x * 128;
    const int col0 = blockIdx.y * 128;
    const unsigned short* __restrict__ A = Abf + (size_t)m * 4096 * 512;
    const unsigned short* __restrict__ Bw = Wbf + (size_t)m * 2048 * 512;
    const int K = 512;
    const int NT = K / 32;

    const int tid = threadIdx.x;
    const int lane = tid & 63;
    const int wave = tid >> 6;
    const int wr = wave >> 1, wc = wave & 1;
    const int lr16 = lane & 15;
    const int kk8 = (lane >> 4) << 3;

    __shared__ __align__(16) short sA[2][128 * 32];
    __shared__ __align__(16) short sB[2][128 * 32];

    f32x4 acc[4][4];
    #pragma unroll
    for (int i = 0; i < 4; ++i)
        #pragma unroll
        for (int j = 0; j < 4; ++j)
            acc[i][j] = (f32x4){0.f, 0.f, 0.f, 0.f};

    #define STAGE(buf, t)                                                        \
        {                                                                        \
            const int k0 = (t) * 32;                                             \
            _Pragma("unroll")                                                    \
            for (int i = 0; i < 2; ++i) {                                        \
                const int c = i * 256 + tid;                                     \
                const int rowc = c >> 2;                                         \
                const int kc = (c & 3) << 3;                                     \
                gload16(A + (size_t)(row0 + rowc) * K + k0 + kc,                 \
                        &sA[buf][rowc * 32 + kc]);                               \
                gload16(Bw + (size_t)(col0 + rowc) * K + k0 + kc,                \
                        &sB[buf][rowc * 32 + kc]);                               \
            }                                                                    \
        }

    #define COMPUTE(buf)                                                         \
        {                                                                        \
            bf16x8 af[4], bfr[4];                                                \
            _Pragma("unroll")                                                    \
            for (int i = 0; i < 4; ++i) {                                        \
                af[i]  = *(const bf16x8*)&sA[buf][(wr * 64 + i * 16 + lr16) * 32 + kk8]; \
                bfr[i] = *(const bf16x8*)&sB[buf][(wc * 64 + i * 16 + lr16) * 32 + kk8]; \
            }                                                                    \
            _Pragma("unroll")                                                    \
            for (int i = 0; i < 4; ++i)                                          \
                _Pragma("unroll")                                                \
                for (int j = 0; j < 4; ++j)                                      \
                    acc[i][j] = __builtin_amdgcn_mfma_f32_16x16x32_bf16(         \
                        af[i], bfr[j], acc[i][j], 0, 0, 0);                      \
        }

    STAGE(0, 0);
    __syncthreads();
    int cur = 0;
    for (int t = 0; t < NT - 1; ++t) {
        STAGE(cur ^ 1, t + 1);
        COMPUTE(cur);
        __syncthreads();
        cur ^= 1;
    }
    COMPUTE(cur);

    const bool isX = (col0 < 1024);
    #pragma unroll
    for (int i = 0; i < 4; ++i) {
        const int rb = row0 + wr * 64 + i * 16 + ((lane >> 4) << 2);
        #pragma unroll
        for (int j = 0; j < 4; ++j) {
            const int cc = col0 + wc * 64 + j * 16 + lr16;
            #pragma unroll
            for (int r = 0; r < 4; ++r) {
                const float v = acc[i][j][r];
                const int row = rb + r;
                if (isX)
                    xb[((size_t)m * 4096 + row) * 1024 + cc] = v;
                else
                    zbf[((size_t)m * 4096 + row) * 1024 + (cc - 1024)] =
                        __float2bfloat16(v);
            }
        }
    }
    #undef STAGE
    #undef COMPUTE
}

// ---------------------------------------------------------------------------
// K2: depthwise 3x3 conv (SAME) + bias + BN + SiLU. Spatial 16x8, n = h*8+w.
// ---------------------------------------------------------------------------
__global__ __launch_bounds__(256) void k_conv(
    const float* __restrict__ x, const float* __restrict__ cw,
    const float* __restrict__ cb, const float* __restrict__ gm,
    const float* __restrict__ bt, const float* __restrict__ mn,
    const float* __restrict__ vr, float* __restrict__ out)
{
    const int nIdx = blockIdx.x;       // 0..127
    const int b = blockIdx.y;
    const int m = blockIdx.z;
    const int h = nIdx >> 3, w = nIdx & 7;
    const float* __restrict__ xm = x + ((size_t)(m * NB + b)) * NN * NDI;

    #pragma unroll
    for (int q = 0; q < 4; ++q) {
        const int di = (q << 8) + threadIdx.x;
        const float* __restrict__ wp = cw + ((size_t)(m * NDI + di)) * 9;
        float s = 0.f;
        #pragma unroll
        for (int kh = 0; kh < 3; ++kh) {
            const int hh = h + kh - 1;
            if ((unsigned)hh < 16u) {
                #pragma unroll
                for (int kw = 0; kw < 3; ++kw) {
                    const int ww = w + kw - 1;
                    if ((unsigned)ww < 8u)
                        s = fmaf(xm[(size_t)(hh * 8 + ww) * NDI + di],
                                 wp[kh * 3 + kw], s);
                }
            }
        }
        const int c = m * NDI + di;
        const float scale = gm[c] * rsqrtf(vr[c] + 1e-5f);
        const float y = (s + cb[c] - mn[c]) * scale + bt[c];
        out[((size_t)(m * NB + b) * NN + nIdx) * NDI + di] = y / (1.f + __expf(-y));
    }
}

// ---------------------------------------------------------------------------
// K3: xproj (fp32 vector GEMM). xd[s,row,e], e in [0,64).
// ---------------------------------------------------------------------------
__global__ __launch_bounds__(256) void k_xproj(
    const float* __restrict__ xc, const float* __restrict__ xw,
    float* __restrict__ xd)
{
    const int s = blockIdx.z;
    const int m = s % 3;
    const bool rev = s >= 3;
    const float* __restrict__ A = xc + (size_t)m * 4096 * NDI;
    const float* __restrict__ Bw = xw + (size_t)s * 64 * NDI;
    const int row0 = blockIdx.x * 64;
    const int tid = threadIdx.x;
    const int tx = tid & 15, ty = tid >> 4;
    const int lr = tid >> 2;
    const int lk = (tid & 3) << 2;

    __shared__ float As[16][64];
    __shared__ float Bs[16][64];
    float acc[4][4] = {};

    const int arow = row0 + lr;
    const int ab = arow >> 7, at = arow & 127;
    const int srow = ab * NN + (rev ? (NN - 1 - at) : at);

    for (int k0 = 0; k0 < NDI; k0 += 16) {
        const float4 av = *(const float4*)(A + (size_t)srow * NDI + k0 + lk);
        const float4 bv = *(const float4*)(Bw + (size_t)lr * NDI + k0 + lk);
        __syncthreads();
        As[lk + 0][lr] = av.x; As[lk + 1][lr] = av.y;
        As[lk + 2][lr] = av.z; As[lk + 3][lr] = av.w;
        Bs[lk + 0][lr] = bv.x; Bs[lk + 1][lr] = bv.y;
        Bs[lk + 2][lr] = bv.z; Bs[lk + 3][lr] = bv.w;
        __syncthreads();
        #pragma unroll
        for (int kk = 0; kk < 16; ++kk) {
            const float4 a4 = *(const float4*)&As[kk][ty << 2];
            const float4 b4 = *(const float4*)&Bs[kk][tx << 2];
            const float ar[4] = {a4.x, a4.y, a4.z, a4.w};
            const float br[4] = {b4.x, b4.y, b4.z, b4.w};
            #pragma unroll
            for (int i = 0; i < 4; ++i)
                #pragma unroll
                for (int j = 0; j < 4; ++j)
                    acc[i][j] = fmaf(ar[i], br[j], acc[i][j]);
        }
    }
    const int e0 = tx << 2;
    #pragma unroll
    for (int i = 0; i < 4; ++i) {
        const int row = row0 + (ty << 2) + i;
        *(float4*)(xd + ((size_t)s * 4096 + row) * 64 + e0) =
            make_float4(acc[i][0], acc[i][1], acc[i][2], acc[i][3]);
    }
}

// ---------------------------------------------------------------------------
// K3b: delta precompute (fully parallel; hoisted out of the sequential scan).
// delta[s,b,t,d] = softplus(xd[s,b,t,0:32] . dtw[s,d,:] + dtb[s,d]), f16 out.
// ---------------------------------------------------------------------------
__global__ __launch_bounds__(256) void k_delta(
    const float* __restrict__ xd, const float* __restrict__ dtw,
    const float* __restrict__ dtb, __half* __restrict__ delta)
{
    const int s = blockIdx.z, b = blockIdx.y;
    const int d = blockIdx.x * 256 + threadIdx.x;
    const float L2E = 1.442695040888963f;

    float wdt[NDR];
    const float* __restrict__ wp = dtw + ((size_t)s * NDI + d) * NDR;
    #pragma unroll
    for (int r = 0; r < NDR; r += 4)
        *(float4*)&wdt[r] = *(const float4*)(wp + r);
    const float bias = dtb[s * NDI + d];

    const float* __restrict__ xrow = xd + ((size_t)(s * NB + b)) * NN * 64;
    __half* __restrict__ dout = delta + ((size_t)(s * NB + b)) * NN * NDI + d;

    for (int t = 0; t < NN; ++t) {
        const float* __restrict__ xr = xrow + (size_t)t * 64;  // wave-uniform
        float dl = bias;
        #pragma unroll
        for (int q = 0; q < 8; ++q) {
            const float4 v = *(const float4*)(xr + q * 4);
            dl = fmaf(v.x, wdt[q * 4 + 0], dl);
            dl = fmaf(v.y, wdt[q * 4 + 1], dl);
            dl = fmaf(v.z, wdt[q * 4 + 2], dl);
            dl = fmaf(v.w, wdt[q * 4 + 3], dl);
        }
        const float e = exp2f(-fabsf(dl) * L2E);
        const float dlt = fmaxf(dl, 0.f) + __logf(1.f + e);
        dout[(size_t)t * NDI] = __float2half(dlt);
    }
}

// ---------------------------------------------------------------------------
// K4: selective scan v4: state-split. Lane pair (2k,2k+1) owns channel
// d = base + k; each lane handles 8 of the 16 states. y reduced across the
// pair with one full-rate DPP add. delta precomputed (f16). 6 blocks/CU.
// ---------------------------------------------------------------------------
__global__ __launch_bounds__(256) void k_scan(
    const float* __restrict__ xc, const float* __restrict__ xd,
    const __half* __restrict__ deltab,
    const float* __restrict__ alog, const float* __restrict__ Dp,
    float* __restrict__ y6)
{
    const int s = blockIdx.z, b = blockIdx.y;
    const int tid = threadIdx.x;
    const int jg = tid & 1;                       // state half
    const int d = blockIdx.x * 128 + (tid >> 1);  // channel
    const int m = (s >= 3) ? (s - 3) : s;
    const bool rev = s >= 3;
    const float L2E = 1.442695040888963f;

    float a2[8], h[8];
    const float* __restrict__ ap = alog + ((size_t)s * NDI + d) * NDS + jg * 8;
    #pragma unroll
    for (int j = 0; j < 8; j += 4) {
        const float4 v = *(const float4*)(ap + j);
        a2[j]     = -__expf(v.x) * L2E;
        a2[j + 1] = -__expf(v.y) * L2E;
        a2[j + 2] = -__expf(v.z) * L2E;
        a2[j + 3] = -__expf(v.w) * L2E;
        h[j] = h[j + 1] = h[j + 2] = h[j + 3] = 0.f;
    }
    const float Dd = Dp[s * NDI + d];

    const float* __restrict__ up = xc + ((size_t)(m * NB + b)) * NN * NDI + d;
    const float* __restrict__ xrow = xd + ((size_t)(s * NB + b)) * NN * 64 + 32 + jg * 8;
    const __half* __restrict__ dp = deltab + ((size_t)(s * NB + b)) * NN * NDI + d;
    float* __restrict__ yp = y6 + ((size_t)(s * NB + b)) * NN * NDI + d;

    int un = (rev ? (NN - 1) : 0) * NDI;
    const int ustep = rev ? -NDI : NDI;
    const bool writer = (jg == 0);

    for (int t = 0; t < NN; ++t) {
        const float delta = __half2float(dp[(size_t)t * NDI]);
        const float u = up[un];
        un += ustep;

        const float* __restrict__ xr = xrow + (size_t)t * 64;
        float Bj[8], Cj[8];
        *(float4*)&Bj[0] = *(const float4*)(xr);
        *(float4*)&Bj[4] = *(const float4*)(xr + 4);
        *(float4*)&Cj[0] = *(const float4*)(xr + 16);
        *(float4*)&Cj[4] = *(const float4*)(xr + 20);

        const float du = delta * u;
        float y = 0.f;
        #pragma unroll
        for (int j = 0; j < 8; ++j) {
            const float dA = exp2f(delta * a2[j]);
            h[j] = fmaf(dA, h[j], du * Bj[j]);
            y = fmaf(h[j], Cj[j], y);
        }
        y = pair_sum(y);
        if (writer) yp[(size_t)t * NDI] = fmaf(u, Dd, y);
    }
}

// ---------------------------------------------------------------------------
// K5: LN + fwd/rev combine + SiLU(z) gating, float4-vectorized.
// ---------------------------------------------------------------------------
__global__ __launch_bounds__(256) void k_combine(
    const float* __restrict__ y6, const __hip_bfloat16* __restrict__ zbf,
    const float* __restrict__ g, const float* __restrict__ be,
    __hip_bfloat16* __restrict__ yg)
{
    const int t = blockIdx.x, b = blockIdx.y, m = blockIdx.z;
    const int tid = threadIdx.x;
    const int dd = tid << 2;
    const float* __restrict__ rowf = y6 + ((size_t)(m * NB + b) * NN + t) * NDI;
    const float* __restrict__ rowr =
        y6 + ((size_t)((m + 3) * NB + b) * NN + (NN - 1 - t)) * NDI;
    const __hip_bfloat16* __restrict__ zrow =
        zbf + ((size_t)(m * NB + b) * NN + t) * NDI;

    const float4 vf = *(const float4*)(rowf + dd);
    const float4 vr = *(const float4*)(rowr + dd);
    float sf = vf.x + vf.y + vf.z + vf.w;
    float qf = vf.x * vf.x + vf.y * vf.y + vf.z * vf.z + vf.w * vf.w;
    float sr = vr.x + vr.y + vr.z + vr.w;
    float qr = vr.x * vr.x + vr.y * vr.y + vr.z * vr.z + vr.w * vr.w;

    #pragma unroll
    for (int off = 32; off > 0; off >>= 1) {
        sf += __shfl_down(sf, off, 64);
        qf += __shfl_down(qf, off, 64);
        sr += __shfl_down(sr, off, 64);
        qr += __shfl_down(qr, off, 64);
    }
    __shared__ float red[4][4];
    const int wv = tid >> 6;
    if ((tid & 63) == 0) { red[wv][0] = sf; red[wv][1] = qf; red[wv][2] = sr; red[wv][3] = qr; }
    __syncthreads();
    const float tsf = red[0][0] + red[1][0] + red[2][0] + red[3][0];
    const float tqf = red[0][1] + red[1][1] + red[2][1] + red[3][1];
    const float tsr = red[0][2] + red[1][2] + red[2][2] + red[3][2];
    const float tqr = red[0][3] + red[1][3] + red[2][3] + red[3][3];
    const float muf = tsf * (1.f / NDI);
    const float varf = tqf * (1.f / NDI) - muf * muf;
    const float rsf = rsqrtf(varf + 1e-5f);
    const float mur = tsr * (1.f / NDI);
    const float varr = tqr * (1.f / NDI) - mur * mur;
    const float rsr = rsqrtf(varr + 1e-5f);

    const float4 gf = *(const float4*)(g + m * NDI + dd);
    const float4 bf = *(const float4*)(be + m * NDI + dd);
    const float4 gr = *(const float4*)(g + (m + 3) * NDI + dd);
    const float4 br = *(const float4*)(be + (m + 3) * NDI + dd);
    const ushort4 zu = *(const ushort4*)(zrow + dd);

    float lf[4], lr2[4], zv[4];
    lf[0] = (vf.x - muf) * rsf * gf.x + bf.x;
    lf[1] = (vf.y - muf) * rsf * gf.y + bf.y;
    lf[2] = (vf.z - muf) * rsf * gf.z + bf.z;
    lf[3] = (vf.w - muf) * rsf * gf.w + bf.w;
    lr2[0] = (vr.x - mur) * rsr * gr.x + br.x;
    lr2[1] = (vr.y - mur) * rsr * gr.y + br.y;
    lr2[2] = (vr.z - mur) * rsr * gr.z + br.z;
    lr2[3] = (vr.w - mur) * rsr * gr.w + br.w;
    zv[0] = __bfloat162float(*(const __hip_bfloat16*)&zu.x);
    zv[1] = __bfloat162float(*(const __hip_bfloat16*)&zu.y);
    zv[2] = __bfloat162float(*(const __hip_bfloat16*)&zu.z);
    zv[3] = __bfloat162float(*(const __hip_bfloat16*)&zu.w);

    ushort4 o;
    unsigned short* op = (unsigned short*)&o;
    #pragma unroll
    for (int q = 0; q < 4; ++q) {
        const float sig = 1.f / (1.f + __expf(-zv[q]));
        op[q] = f2bf((lf[q] + lr2[q]) * zv[q] * sig);
    }
    *(ushort4*)(yg + ((size_t)(m * NB + b) * NN + t) * NDI + dd) = o;
}

// ---------------------------------------------------------------------------
// K6: out_proj as bf16 MFMA GEMM + fp32 residual add.
// ---------------------------------------------------------------------------
__global__ __launch_bounds__(256) void k_gemm_outproj(
    const unsigned short* __restrict__ Abf,
    const unsigned short* __restrict__ Wbf,
    const float* __restrict__ rr, const float* __restrict__ nn,
    const float* __restrict__ tt, float* __restrict__ out)
{
    const int row0 = blockIdx.x * 128;   // over 12288
    const int col0 = blockIdx.y * 128;   // over 512
    const int K = 1024;
    const int NT = K / 32;

    const int tid = threadIdx.x;
    const int lane = tid & 63;
    const int wave = tid >> 6;
    const int wr = wave >> 1, wc = wave & 1;
    const int lr16 = lane & 15;
    const int kk8 = (lane >> 4) << 3;

    __shared__ __align__(16) short sA[2][128 * 32];
    __shared__ __align__(16) short sB[2][128 * 32];

    f32x4 acc[4][4];
    #pragma unroll
    for (int i = 0; i < 4; ++i)
        #pragma unroll
        for (int j = 0; j < 4; ++j)
            acc[i][j] = (f32x4){0.f, 0.f, 0.f, 0.f};

    #define STAGE(buf, t)                                                        \
        {                                                                        \
            const int k0 = (t) * 32;                                             \
            _Pragma("unroll")                                                    \
            for (int i = 0; i < 2; ++i) {                                        \
                const int c = i * 256 + tid;                                     \
                const int rowc = c >> 2;                                         \
                const int kc = (c & 3) << 3;                                     \
                gload16(Abf + (size_t)(row0 + rowc) * K + k0 + kc,               \
                        &sA[buf][rowc * 32 + kc]);                               \
                gload16(Wbf + (size_t)(col0 + rowc) * K + k0 + kc,               \
                        &sB[buf][rowc * 32 + kc]);                               \
            }                                                                    \
        }

    #define COMPUTE(buf)                                                         \
        {                                                                        \
            bf16x8 af[4], bfr[4];                                                \
            _Pragma("unroll")                                                    \
            for (int i = 0; i < 4; ++i) {                                        \
                af[i]  = *(const bf16x8*)&sA[buf][(wr * 64 + i * 16 + lr16) * 32 + kk8]; \
                bfr[i] = *(const bf16x8*)&sB[buf][(wc * 64 + i * 16 + lr16) * 32 + kk8]; \
            }                                                                    \
            _Pragma("unroll")                                                    \
            for (int i = 0; i < 4; ++i)                                          \
                _Pragma("unroll")                                                \
                for (int j = 0; j < 4; ++j)                                      \
                    acc[i][j] = __builtin_amdgcn_mfma_f32_16x16x32_bf16(         \
                        af[i], bfr[j], acc[i][j], 0, 0, 0);                      \
        }

    STAGE(0, 0);
    __syncthreads();
    int cur = 0;
    for (int t = 0; t < NT - 1; ++t) {
        STAGE(cur ^ 1, t + 1);
        COMPUTE(cur);
        __syncthreads();
        cur ^= 1;
    }
    COMPUTE(cur);

    const int m = row0 >> 12;  // uniform per block (128 | 4096)
    const float* __restrict__ resid = (m == 0) ? rr : (m == 1) ? nn : tt;
    #pragma unroll
    for (int i = 0; i < 4; ++i) {
        const int rb = row0 + wr * 64 + i * 16 + ((lane >> 4) << 2);
        #pragma unroll
        for (int j = 0; j < 4; ++j) {
            const int cc = col0 + wc * 64 + j * 16 + lr16;
            #pragma unroll
            for (int r = 0; r < 4; ++r) {
                const int row = rb + r;
                const int bt = row & 4095;
                out[(size_t)row * ND + cc] =
                    acc[i][j][r] + resid[(size_t)bt * ND + cc];
            }
        }
    }
    #undef STAGE
    #undef COMPUTE
}

// ---------------------------------------------------------------------------
extern "C" void kernel_launch(void* const* d_in, const int* in_sizes, int n_in,
                              void* d_out, int out_size, void* d_ws, size_t ws_size,
                              hipStream_t stream) {
    const float* rr   = (const float*)d_in[0];
    const float* nn   = (const float*)d_in[1];
    const float* tt   = (const float*)d_in[2];
    const float* wip  = (const float*)d_in[3];   // (3,2048,512)
    const float* cw   = (const float*)d_in[4];   // (3,1024,1,3,3)
    const float* cb   = (const float*)d_in[5];
    const float* gm   = (const float*)d_in[6];
    const float* bt   = (const float*)d_in[7];
    const float* mn   = (const float*)d_in[8];
    const float* vr   = (const float*)d_in[9];
    const float* xw   = (const float*)d_in[10];  // (6,64,1024)
    const float* dtw  = (const float*)d_in[11];  // (6,1024,32)
    const float* dtb  = (const float*)d_in[12];
    const float* alog = (const float*)d_in[13];  // (6,1024,16)
    const float* Dp   = (const float*)d_in[14];
    const float* lng  = (const float*)d_in[15];
    const float* lnb  = (const float*)d_in[16];
    const float* wout = (const float*)d_in[17];  // (512,1024)
    float* out = (float*)d_out;

    // workspace layout (bytes), total ~253 MiB
    uint8_t* p = (uint8_t*)d_ws;
    unsigned short* Abf    = (unsigned short*)p;          p += (size_t)3 * 4096 * 512 * 2;   // 12.6 MB
    unsigned short* Wbf    = (unsigned short*)p;          p += (size_t)3 * 2048 * 512 * 2;   //  6.3 MB
    unsigned short* Woutbf = (unsigned short*)p;          p += (size_t)512 * 1024 * 2;       //  1.0 MB
    float*          xb     = (float*)p;                   p += (size_t)3 * 4096 * 1024 * 4;  // 50.3 MB
    __hip_bfloat16* zbf    = (__hip_bfloat16*)p;          p += (size_t)3 * 4096 * 1024 * 2;  // 25.2 MB
    float*          xc     = (float*)p;                   p += (size_t)3 * 4096 * 1024 * 4;  // 50.3 MB
    float*          xdb    = (float*)p;                   p += (size_t)6 * 4096 * 64 * 4;    //  6.3 MB
    float*          y6     = (float*)p;                   p += (size_t)6 * 4096 * 1024 * 4;  // 100.7 MB
    // reuse xb (x fp32 is dead after k_conv): delta f16 (6,32,128,1024) = 50.3 MB
    __half*         deltah = (__half*)xb;
    // reuse xb front again after scan: yg bf16 (3,32,128,1024) = 25.2 MB
    __hip_bfloat16* ygbf   = (__hip_bfloat16*)xb;

    // bf16 conversions
    k_cvt3<<<dim3(2048, 1, 3), 256, 0, stream>>>(rr, nn, tt, Abf, 4096 * 512 / 4);
    k_cvt<<<dim3(2048), 256, 0, stream>>>(wip,  Wbf, 3 * 2048 * 512 / 4);
    k_cvt<<<dim3(512),  256, 0, stream>>>(wout, Woutbf, 512 * 1024 / 4);

    k_gemm_inproj<<<dim3(32, 16, 3), 256, 0, stream>>>(Abf, Wbf, xb, zbf);
    k_conv<<<dim3(128, 32, 3), 256, 0, stream>>>(xb, cw, cb, gm, bt, mn, vr, xc);
    k_xproj<<<dim3(64, 1, 6), 256, 0, stream>>>(xc, xw, xdb);
    k_delta<<<dim3(4, 32, 6), 256, 0, stream>>>(xdb, dtw, dtb, deltah);
    k_scan<<<dim3(8, 32, 6), 256, 0, stream>>>(xc, xdb, deltah, alog, Dp, y6);
    k_combine<<<dim3(128, 32, 3), 256, 0, stream>>>(y6, zbf, lng, lnb, ygbf);
    k_gemm_outproj<<<dim3(96, 4, 1), 256, 0, stream>>>(
        (const unsigned short*)ygbf, Woutbf, rr, nn, tt, out);
}

// Round 7
// 557.978 us; speedup vs baseline: 1.0872x; 1.0872x over previous
//
#include <hip/hip_runtime.h>
#include <hip/hip_bf16.h>
#include <hip/hip_fp16.h>
#include <math.h>

// Problem constants
#define NB 32     // batch
#define NN 128    // sequence (= 16 x 8)
#define ND 512    // model dim
#define NDI 1024  // inner dim
#define NDS 16    // state dim
#define NDR 32    // dt rank

typedef __attribute__((ext_vector_type(8))) __bf16 bf16x8;
typedef __attribute__((ext_vector_type(4))) float f32x4;

typedef __attribute__((address_space(3))) void lds_void;
typedef const __attribute__((address_space(1))) void glob_void;

__device__ __forceinline__ void gload16(const void* g, void* l) {
    __builtin_amdgcn_global_load_lds((glob_void*)g, (lds_void*)l, 16, 0, 0);
}

__device__ __forceinline__ unsigned short f2bf(float x) {
    __hip_bfloat16 h = __float2bfloat16(x);
    return *(unsigned short*)&h;
}
__device__ __forceinline__ float bf2f(unsigned short v) {
    return __uint_as_float(((unsigned int)v) << 16);
}
__device__ __forceinline__ float hf2f(unsigned short v) {
    __half h = *(__half*)&v;
    return __half2float(h);
}

// full-rate DPP pair-sum: adds value from the xor-1 lane (quad_perm [1,0,3,2])
__device__ __forceinline__ float pair_sum(float y) {
    const int sw = __builtin_amdgcn_mov_dpp(__float_as_int(y), 0xB1, 0xF, 0xF, true);
    return y + __int_as_float(sw);
}

// ---------------------------------------------------------------------------
// K0: fp32 -> bf16 conversion (RTNE). k_cvt3 handles r,n,t in one launch.
// ---------------------------------------------------------------------------
__global__ __launch_bounds__(256) void k_cvt(
    const float* __restrict__ s, unsigned short* __restrict__ d, int n4)
{
    for (int i = blockIdx.x * 256 + threadIdx.x; i < n4; i += gridDim.x * 256) {
        const float4 v = ((const float4*)s)[i];
        ushort4 o;
        o.x = f2bf(v.x); o.y = f2bf(v.y); o.z = f2bf(v.z); o.w = f2bf(v.w);
        ((ushort4*)d)[i] = o;
    }
}

__global__ __launch_bounds__(256) void k_cvt3(
    const float* __restrict__ rr, const float* __restrict__ nn,
    const float* __restrict__ tt, unsigned short* __restrict__ d, int n4)
{
    const int z = blockIdx.z;
    const float* __restrict__ s = (z == 0) ? rr : (z == 1) ? nn : tt;
    unsigned short* __restrict__ dz = d + (size_t)z * n4 * 4;
    for (int i = blockIdx.x * 256 + threadIdx.x; i < n4; i += gridDim.x * 256) {
        const float4 v = ((const float4*)s)[i];
        ushort4 o;
        o.x = f2bf(v.x); o.y = f2bf(v.y); o.z = f2bf(v.z); o.w = f2bf(v.w);
        ((ushort4*)dz)[i] = o;
    }
}

// ---------------------------------------------------------------------------
// K1: in_proj as bf16 MFMA GEMM (m97 structure). Tile 128x128, BK=32.
// ---------------------------------------------------------------------------
__global__ __launch_bounds__(256) void k_gemm_inproj(
    const unsigned short* __restrict__ Abf,
    const unsigned short* __restrict__ Wbf,
    float* __restrict__ xb, __hip_bfloat16* __restrict__ zbf)
{
    const int m = blockIdx.z;
    const int row0 = blockIdx.x * 128;
    const int col0 = blockIdx.y * 128;
    const unsigned short* __restrict__ A = Abf + (size_t)m * 4096 * 512;
    const unsigned short* __restrict__ Bw = Wbf + (size_t)m * 2048 * 512;
    const int K = 512;
    const int NT = K / 32;

    const int tid = threadIdx.x;
    const int lane = tid & 63;
    const int wave = tid >> 6;
    const int wr = wave >> 1, wc = wave & 1;
    const int lr16 = lane & 15;
    const int kk8 = (lane >> 4) << 3;

    __shared__ __align__(16) short sA[2][128 * 32];
    __shared__ __align__(16) short sB[2][128 * 32];

    f32x4 acc[4][4];
    #pragma unroll
    for (int i = 0; i < 4; ++i)
        #pragma unroll
        for (int j = 0; j < 4; ++j)
            acc[i][j] = (f32x4){0.f, 0.f, 0.f, 0.f};

    #define STAGE(buf, t)                                                        \
        {                                                                        \
            const int k0 = (t) * 32;                                             \
            _Pragma("unroll")                                                    \
            for (int i = 0; i < 2; ++i) {                                        \
                const int c = i * 256 + tid;                                     \
                const int rowc = c >> 2;                                         \
                const int kc = (c & 3) << 3;                                     \
                gload16(A + (size_t)(row0 + rowc) * K + k0 + kc,                 \
                        &sA[buf][rowc * 32 + kc]);                               \
                gload16(Bw + (size_t)(col0 + rowc) * K + k0 + kc,                \
                        &sB[buf][rowc * 32 + kc]);                               \
            }                                                                    \
        }

    #define COMPUTE(buf)                                                         \
        {                                                                        \
            bf16x8 af[4], bfr[4];                                                \
            _Pragma("unroll")                                                    \
            for (int i = 0; i < 4; ++i) {                                        \
                af[i]  = *(const bf16x8*)&sA[buf][(wr * 64 + i * 16 + lr16) * 32 + kk8]; \
                bfr[i] = *(const bf16x8*)&sB[buf][(wc * 64 + i * 16 + lr16) * 32 + kk8]; \
            }                                                                    \
            _Pragma("unroll")                                                    \
            for (int i = 0; i < 4; ++i)                                          \
                _Pragma("unroll")                                                \
                for (int j = 0; j < 4; ++j)                                      \
                    acc[i][j] = __builtin_amdgcn_mfma_f32_16x16x32_bf16(         \
                        af[i], bfr[j], acc[i][j], 0, 0, 0);                      \
        }

    STAGE(0, 0);
    __syncthreads();
    int cur = 0;
    for (int t = 0; t < NT - 1; ++t) {
        STAGE(cur ^ 1, t + 1);
        COMPUTE(cur);
        __syncthreads();
        cur ^= 1;
    }
    COMPUTE(cur);

    const bool isX = (col0 < 1024);
    #pragma unroll
    for (int i = 0; i < 4; ++i) {
        const int rb = row0 + wr * 64 + i * 16 + ((lane >> 4) << 2);
        #pragma unroll
        for (int j = 0; j < 4; ++j) {
            const int cc = col0 + wc * 64 + j * 16 + lr16;
            #pragma unroll
            for (int r = 0; r < 4; ++r) {
                const float v = acc[i][j][r];
                const int row = rb + r;
                if (isX)
                    xb[((size_t)m * 4096 + row) * 1024 + cc] = v;
                else
                    zbf[((size_t)m * 4096 + row) * 1024 + (cc - 1024)] =
                        __float2bfloat16(v);
            }
        }
    }
    #undef STAGE
    #undef COMPUTE
}

// ---------------------------------------------------------------------------
// K2: depthwise 3x3 conv (SAME) + bias + BN + SiLU -> bf16 output.
// ---------------------------------------------------------------------------
__global__ __launch_bounds__(256) void k_conv(
    const float* __restrict__ x, const float* __restrict__ cw,
    const float* __restrict__ cb, const float* __restrict__ gm,
    const float* __restrict__ bt, const float* __restrict__ mn,
    const float* __restrict__ vr, unsigned short* __restrict__ out)
{
    const int nIdx = blockIdx.x;       // 0..127
    const int b = blockIdx.y;
    const int m = blockIdx.z;
    const int h = nIdx >> 3, w = nIdx & 7;
    const float* __restrict__ xm = x + ((size_t)(m * NB + b)) * NN * NDI;

    #pragma unroll
    for (int q = 0; q < 4; ++q) {
        const int di = (q << 8) + threadIdx.x;
        const float* __restrict__ wp = cw + ((size_t)(m * NDI + di)) * 9;
        float s = 0.f;
        #pragma unroll
        for (int kh = 0; kh < 3; ++kh) {
            const int hh = h + kh - 1;
            if ((unsigned)hh < 16u) {
                #pragma unroll
                for (int kw = 0; kw < 3; ++kw) {
                    const int ww = w + kw - 1;
                    if ((unsigned)ww < 8u)
                        s = fmaf(xm[(size_t)(hh * 8 + ww) * NDI + di],
                                 wp[kh * 3 + kw], s);
                }
            }
        }
        const int c = m * NDI + di;
        const float scale = gm[c] * rsqrtf(vr[c] + 1e-5f);
        const float y = (s + cb[c] - mn[c]) * scale + bt[c];
        out[((size_t)(m * NB + b) * NN + nIdx) * NDI + di] =
            f2bf(y / (1.f + __expf(-y)));
    }
}

// ---------------------------------------------------------------------------
// K3: xproj as bf16 MFMA GEMM. A = xcbf [3][4096][1024] (row remap for rev),
// B = xwbf [6][64][1024]. C = xd fp32 [6][4096][64]. Tile 128x64, BK=32.
// ---------------------------------------------------------------------------
__global__ __launch_bounds__(256) void k_xproj(
    const unsigned short* __restrict__ xcbf,
    const unsigned short* __restrict__ xwbf,
    float* __restrict__ xd)
{
    const int s = blockIdx.z;
    const int m = (s >= 3) ? (s - 3) : s;
    const bool rev = s >= 3;
    const unsigned short* __restrict__ A = xcbf + (size_t)m * 4096 * 1024;
    const unsigned short* __restrict__ Bw = xwbf + (size_t)s * 64 * 1024;
    const int row0 = blockIdx.x * 128;
    const int NT = 32;  // K=1024 / 32

    const int tid = threadIdx.x;
    const int lane = tid & 63;
    const int wave = tid >> 6;
    const int wr = wave >> 1, wc = wave & 1;
    const int lr16 = lane & 15;
    const int kk8 = (lane >> 4) << 3;

    __shared__ __align__(16) short sA[2][128 * 32];
    __shared__ __align__(16) short sB[2][64 * 32];

    f32x4 acc[4][2];
    #pragma unroll
    for (int i = 0; i < 4; ++i)
        #pragma unroll
        for (int j = 0; j < 2; ++j)
            acc[i][j] = (f32x4){0.f, 0.f, 0.f, 0.f};

    #define STAGEX(buf, t)                                                       \
        {                                                                        \
            const int k0 = (t) * 32;                                             \
            _Pragma("unroll")                                                    \
            for (int i = 0; i < 2; ++i) {                                        \
                const int c = i * 256 + tid;                                     \
                const int rowc = c >> 2;                                         \
                const int kc = (c & 3) << 3;                                     \
                const int arow = row0 + rowc;                                    \
                const int ab = arow >> 7, at = arow & 127;                       \
                const int srow = ab * NN + (rev ? (NN - 1 - at) : at);           \
                gload16(A + (size_t)srow * 1024 + k0 + kc,                       \
                        &sA[buf][rowc * 32 + kc]);                               \
            }                                                                    \
            {                                                                    \
                const int rowc = tid >> 2;                                       \
                const int kc = (tid & 3) << 3;                                   \
                gload16(Bw + (size_t)rowc * 1024 + k0 + kc,                      \
                        &sB[buf][rowc * 32 + kc]);                               \
            }                                                                    \
        }

    #define COMPUTEX(buf)                                                        \
        {                                                                        \
            bf16x8 af[4], bfr[2];                                                \
            _Pragma("unroll")                                                    \
            for (int i = 0; i < 4; ++i)                                          \
                af[i] = *(const bf16x8*)&sA[buf][(wr * 64 + i * 16 + lr16) * 32 + kk8]; \
            _Pragma("unroll")                                                    \
            for (int j = 0; j < 2; ++j)                                          \
                bfr[j] = *(const bf16x8*)&sB[buf][(wc * 32 + j * 16 + lr16) * 32 + kk8]; \
            _Pragma("unroll")                                                    \
            for (int i = 0; i < 4; ++i)                                          \
                _Pragma("unroll")                                                \
                for (int j = 0; j < 2; ++j)                                      \
                    acc[i][j] = __builtin_amdgcn_mfma_f32_16x16x32_bf16(         \
                        af[i], bfr[j], acc[i][j], 0, 0, 0);                      \
        }

    STAGEX(0, 0);
    __syncthreads();
    int cur = 0;
    for (int t = 0; t < NT - 1; ++t) {
        STAGEX(cur ^ 1, t + 1);
        COMPUTEX(cur);
        __syncthreads();
        cur ^= 1;
    }
    COMPUTEX(cur);

    #pragma unroll
    for (int i = 0; i < 4; ++i) {
        const int rb = row0 + wr * 64 + i * 16 + ((lane >> 4) << 2);
        #pragma unroll
        for (int j = 0; j < 2; ++j) {
            const int cc = wc * 32 + j * 16 + lr16;
            #pragma unroll
            for (int r = 0; r < 4; ++r) {
                const int row = rb + r;
                xd[((size_t)s * 4096 + row) * 64 + cc] = acc[i][j][r];
            }
        }
    }
    #undef STAGEX
    #undef COMPUTEX
}

// ---------------------------------------------------------------------------
// K3b: delta precompute, TRANSPOSED f16 output [s,b,d,t] so the scan can
// load 8 steps per 16B. One block per (dq,b,s); thread owns d, loops t.
// ---------------------------------------------------------------------------
__global__ __launch_bounds__(256) void k_delta(
    const float* __restrict__ xd, const float* __restrict__ dtw,
    const float* __restrict__ dtb, unsigned short* __restrict__ deltaT)
{
    const int s = blockIdx.z, b = blockIdx.y;
    const int d = blockIdx.x * 256 + threadIdx.x;
    const float L2E = 1.442695040888963f;

    float wdt[NDR];
    const float* __restrict__ wp = dtw + ((size_t)s * NDI + d) * NDR;
    #pragma unroll
    for (int r = 0; r < NDR; r += 4)
        *(float4*)&wdt[r] = *(const float4*)(wp + r);
    const float bias = dtb[s * NDI + d];

    const float* __restrict__ xrow = xd + ((size_t)(s * NB + b)) * NN * 64;
    unsigned short* __restrict__ dout =
        deltaT + (((size_t)(s * NB + b)) * NDI + d) * NN;

    for (int t8 = 0; t8 < NN / 8; ++t8) {
        ushort4 o0, o1;
        unsigned short* op0 = (unsigned short*)&o0;
        unsigned short* op1 = (unsigned short*)&o1;
        #pragma unroll
        for (int k = 0; k < 8; ++k) {
            const int t = t8 * 8 + k;
            const float* __restrict__ xr = xrow + (size_t)t * 64;  // uniform
            float dl = bias;
            #pragma unroll
            for (int q = 0; q < 8; ++q) {
                const float4 v = *(const float4*)(xr + q * 4);
                dl = fmaf(v.x, wdt[q * 4 + 0], dl);
                dl = fmaf(v.y, wdt[q * 4 + 1], dl);
                dl = fmaf(v.z, wdt[q * 4 + 2], dl);
                dl = fmaf(v.w, wdt[q * 4 + 3], dl);
            }
            const float e = exp2f(-fabsf(dl) * L2E);
            const float dlt = fmaxf(dl, 0.f) + __logf(1.f + e);
            const __half hv = __float2half(dlt);
            if (k < 4) op0[k] = *(const unsigned short*)&hv;
            else       op1[k - 4] = *(const unsigned short*)&hv;
        }
        *(ushort4*)(dout + t8 * 8) = o0;
        *(ushort4*)(dout + t8 * 8 + 4) = o1;
    }
}

// ---------------------------------------------------------------------------
// K4: selective scan v5: state-split lane pairs + software pipeline.
// B/C/u for step t+1 prefetched during compute of step t; delta loaded
// 8 steps at a time (16B, per-lane contiguous). u from bf16.
// ---------------------------------------------------------------------------
__global__ __launch_bounds__(256) void k_scan(
    const unsigned short* __restrict__ xcbf, const float* __restrict__ xd,
    const unsigned short* __restrict__ deltaT,
    const float* __restrict__ alog, const float* __restrict__ Dp,
    float* __restrict__ y6)
{
    const int s = blockIdx.z, b = blockIdx.y;
    const int tid = threadIdx.x;
    const int jg = tid & 1;                       // state half
    const int d = blockIdx.x * 128 + (tid >> 1);  // channel
    const int m = (s >= 3) ? (s - 3) : s;
    const bool rev = s >= 3;
    const float L2E = 1.442695040888963f;

    float a2[8], h[8];
    const float* __restrict__ ap = alog + ((size_t)s * NDI + d) * NDS + jg * 8;
    #pragma unroll
    for (int j = 0; j < 8; j += 4) {
        const float4 v = *(const float4*)(ap + j);
        a2[j]     = -__expf(v.x) * L2E;
        a2[j + 1] = -__expf(v.y) * L2E;
        a2[j + 2] = -__expf(v.z) * L2E;
        a2[j + 3] = -__expf(v.w) * L2E;
        h[j] = h[j + 1] = h[j + 2] = h[j + 3] = 0.f;
    }
    const float Dd = Dp[s * NDI + d];

    const unsigned short* __restrict__ up =
        xcbf + ((size_t)(m * NB + b)) * NN * NDI + d;
    const float* __restrict__ xr =
        xd + ((size_t)(s * NB + b)) * NN * 64 + 32 + jg * 8;
    const unsigned short* __restrict__ dpT =
        deltaT + (((size_t)(s * NB + b)) * NDI + d) * NN;
    float* __restrict__ yp = y6 + ((size_t)(s * NB + b)) * NN * NDI + d;

    int un = (rev ? (NN - 1) : 0) * NDI;
    const int ustep = rev ? -NDI : NDI;
    const bool writer = (jg == 0);

    // prologue: t=0 inputs + first two delta groups
    uint4 dv  = *(const uint4*)dpT;
    uint4 dvn = *(const uint4*)(dpT + 8);
    float u = bf2f(up[un]); un += ustep;
    float4 B0 = *(const float4*)(xr);
    float4 B1 = *(const float4*)(xr + 4);
    float4 C0 = *(const float4*)(xr + 16);
    float4 C1 = *(const float4*)(xr + 20);

    for (int t8 = 0; t8 < NN / 8; ++t8) {
        #pragma unroll
        for (int k = 0; k < 8; ++k) {
            // prefetch step t+1 (reads ≤256B past slab end on final step; ws-safe)
            const float* __restrict__ xn = xr + 64;
            const float4 nB0 = *(const float4*)(xn);
            const float4 nB1 = *(const float4*)(xn + 4);
            const float4 nC0 = *(const float4*)(xn + 16);
            const float4 nC1 = *(const float4*)(xn + 20);
            const float u_n = bf2f(up[un]); un += ustep;

            const float delta = hf2f(((const unsigned short*)&dv)[k]);
            const float du = delta * u;
            float y = 0.f;
            #pragma unroll
            for (int j = 0; j < 4; ++j) {
                const float dA = exp2f(delta * a2[j]);
                h[j] = fmaf(dA, h[j], du * ((const float*)&B0)[j]);
                y = fmaf(h[j], ((const float*)&C0)[j], y);
            }
            #pragma unroll
            for (int j = 0; j < 4; ++j) {
                const float dA = exp2f(delta * a2[4 + j]);
                h[4 + j] = fmaf(dA, h[4 + j], du * ((const float*)&B1)[j]);
                y = fmaf(h[4 + j], ((const float*)&C1)[j], y);
            }
            y = pair_sum(y);
            if (writer) yp[(size_t)(t8 * 8 + k) * NDI] = fmaf(u, Dd, y);

            u = u_n; B0 = nB0; B1 = nB1; C0 = nC0; C1 = nC1; xr = xn;
        }
        dv = dvn;
        dvn = *(const uint4*)(dpT + (t8 + 2) * 8);  // reads past only at the tail; ws-safe
    }
}

// ---------------------------------------------------------------------------
// K5: LN + fwd/rev combine + SiLU(z) gating, float4-vectorized.
// ---------------------------------------------------------------------------
__global__ __launch_bounds__(256) void k_combine(
    const float* __restrict__ y6, const __hip_bfloat16* __restrict__ zbf,
    const float* __restrict__ g, const float* __restrict__ be,
    __hip_bfloat16* __restrict__ yg)
{
    const int t = blockIdx.x, b = blockIdx.y, m = blockIdx.z;
    const int tid = threadIdx.x;
    const int dd = tid << 2;
    const float* __restrict__ rowf = y6 + ((size_t)(m * NB + b) * NN + t) * NDI;
    const float* __restrict__ rowr =
        y6 + ((size_t)((m + 3) * NB + b) * NN + (NN - 1 - t)) * NDI;
    const __hip_bfloat16* __restrict__ zrow =
        zbf + ((size_t)(m * NB + b) * NN + t) * NDI;

    const float4 vf = *(const float4*)(rowf + dd);
    const float4 vr = *(const float4*)(rowr + dd);
    float sf = vf.x + vf.y + vf.z + vf.w;
    float qf = vf.x * vf.x + vf.y * vf.y + vf.z * vf.z + vf.w * vf.w;
    float sr = vr.x + vr.y + vr.z + vr.w;
    float qr = vr.x * vr.x + vr.y * vr.y + vr.z * vr.z + vr.w * vr.w;

    #pragma unroll
    for (int off = 32; off > 0; off >>= 1) {
        sf += __shfl_down(sf, off, 64);
        qf += __shfl_down(qf, off, 64);
        sr += __shfl_down(sr, off, 64);
        qr += __shfl_down(qr, off, 64);
    }
    __shared__ float red[4][4];
    const int wv = tid >> 6;
    if ((tid & 63) == 0) { red[wv][0] = sf; red[wv][1] = qf; red[wv][2] = sr; red[wv][3] = qr; }
    __syncthreads();
    const float tsf = red[0][0] + red[1][0] + red[2][0] + red[3][0];
    const float tqf = red[0][1] + red[1][1] + red[2][1] + red[3][1];
    const float tsr = red[0][2] + red[1][2] + red[2][2] + red[3][2];
    const float tqr = red[0][3] + red[1][3] + red[2][3] + red[3][3];
    const float muf = tsf * (1.f / NDI);
    const float varf = tqf * (1.f / NDI) - muf * muf;
    const float rsf = rsqrtf(varf + 1e-5f);
    const float mur = tsr * (1.f / NDI);
    const float varr = tqr * (1.f / NDI) - mur * mur;
    const float rsr = rsqrtf(varr + 1e-5f);

    const float4 gf = *(const float4*)(g + m * NDI + dd);
    const float4 bf = *(const float4*)(be + m * NDI + dd);
    const float4 gr = *(const float4*)(g + (m + 3) * NDI + dd);
    const float4 br = *(const float4*)(be + (m + 3) * NDI + dd);
    const ushort4 zu = *(const ushort4*)(zrow + dd);

    float lf[4], lr2[4], zv[4];
    lf[0] = (vf.x - muf) * rsf * gf.x + bf.x;
    lf[1] = (vf.y - muf) * rsf * gf.y + bf.y;
    lf[2] = (vf.z - muf) * rsf * gf.z + bf.z;
    lf[3] = (vf.w - muf) * rsf * gf.w + bf.w;
    lr2[0] = (vr.x - mur) * rsr * gr.x + br.x;
    lr2[1] = (vr.y - mur) * rsr * gr.y + br.y;
    lr2[2] = (vr.z - mur) * rsr * gr.z + br.z;
    lr2[3] = (vr.w - mur) * rsr * gr.w + br.w;
    zv[0] = bf2f(zu.x);
    zv[1] = bf2f(zu.y);
    zv[2] = bf2f(zu.z);
    zv[3] = bf2f(zu.w);

    ushort4 o;
    unsigned short* op = (unsigned short*)&o;
    #pragma unroll
    for (int q = 0; q < 4; ++q) {
        const float sig = 1.f / (1.f + __expf(-zv[q]));
        op[q] = f2bf((lf[q] + lr2[q]) * zv[q] * sig);
    }
    *(ushort4*)(yg + ((size_t)(m * NB + b) * NN + t) * NDI + dd) = o;
}

// ---------------------------------------------------------------------------
// K6: out_proj as bf16 MFMA GEMM + fp32 residual add.
// ---------------------------------------------------------------------------
__global__ __launch_bounds__(256) void k_gemm_outproj(
    const unsigned short* __restrict__ Abf,
    const unsigned short* __restrict__ Wbf,
    const float* __restrict__ rr, const float* __restrict__ nn,
    const float* __restrict__ tt, float* __restrict__ out)
{
    const int row0 = blockIdx.x * 128;   // over 12288
    const int col0 = blockIdx.y * 128;   // over 512
    const int K = 1024;
    const int NT = K / 32;

    const int tid = threadIdx.x;
    const int lane = tid & 63;
    const int wave = tid >> 6;
    const int wr = wave >> 1, wc = wave & 1;
    const int lr16 = lane & 15;
    const int kk8 = (lane >> 4) << 3;

    __shared__ __align__(16) short sA[2][128 * 32];
    __shared__ __align__(16) short sB[2][128 * 32];

    f32x4 acc[4][4];
    #pragma unroll
    for (int i = 0; i < 4; ++i)
        #pragma unroll
        for (int j = 0; j < 4; ++j)
            acc[i][j] = (f32x4){0.f, 0.f, 0.f, 0.f};

    #define STAGE(buf, t)                                                        \
        {                                                                        \
            const int k0 = (t) * 32;                                             \
            _Pragma("unroll")                                                    \
            for (int i = 0; i < 2; ++i) {                                        \
                const int c = i * 256 + tid;                                     \
                const int rowc = c >> 2;                                         \
                const int kc = (c & 3) << 3;                                     \
                gload16(Abf + (size_t)(row0 + rowc) * K + k0 + kc,               \
                        &sA[buf][rowc * 32 + kc]);                               \
                gload16(Wbf + (size_t)(col0 + rowc) * K + k0 + kc,               \
                        &sB[buf][rowc * 32 + kc]);                               \
            }                                                                    \
        }

    #define COMPUTE(buf)                                                         \
        {                                                                        \
            bf16x8 af[4], bfr[4];                                                \
            _Pragma("unroll")                                                    \
            for (int i = 0; i < 4; ++i) {                                        \
                af[i]  = *(const bf16x8*)&sA[buf][(wr * 64 + i * 16 + lr16) * 32 + kk8]; \
                bfr[i] = *(const bf16x8*)&sB[buf][(wc * 64 + i * 16 + lr16) * 32 + kk8]; \
            }                                                                    \
            _Pragma("unroll")                                                    \
            for (int i = 0; i < 4; ++i)                                          \
                _Pragma("unroll")                                                \
                for (int j = 0; j < 4; ++j)                                      \
                    acc[i][j] = __builtin_amdgcn_mfma_f32_16x16x32_bf16(         \
                        af[i], bfr[j], acc[i][j], 0, 0, 0);                      \
        }

    STAGE(0, 0);
    __syncthreads();
    int cur = 0;
    for (int t = 0; t < NT - 1; ++t) {
        STAGE(cur ^ 1, t + 1);
        COMPUTE(cur);
        __syncthreads();
        cur ^= 1;
    }
    COMPUTE(cur);

    const int m = row0 >> 12;  // uniform per block (128 | 4096)
    const float* __restrict__ resid = (m == 0) ? rr : (m == 1) ? nn : tt;
    #pragma unroll
    for (int i = 0; i < 4; ++i) {
        const int rb = row0 + wr * 64 + i * 16 + ((lane >> 4) << 2);
        #pragma unroll
        for (int j = 0; j < 4; ++j) {
            const int cc = col0 + wc * 64 + j * 16 + lr16;
            #pragma unroll
            for (int r = 0; r < 4; ++r) {
                const int row = rb + r;
                const int bt = row & 4095;
                out[(size_t)row * ND + cc] =
                    acc[i][j][r] + resid[(size_t)bt * ND + cc];
            }
        }
    }
    #undef STAGE
    #undef COMPUTE
}

// ---------------------------------------------------------------------------
extern "C" void kernel_launch(void* const* d_in, const int* in_sizes, int n_in,
                              void* d_out, int out_size, void* d_ws, size_t ws_size,
                              hipStream_t stream) {
    const float* rr   = (const float*)d_in[0];
    const float* nn   = (const float*)d_in[1];
    const float* tt   = (const float*)d_in[2];
    const float* wip  = (const float*)d_in[3];   // (3,2048,512)
    const float* cw   = (const float*)d_in[4];   // (3,1024,1,3,3)
    const float* cb   = (const float*)d_in[5];
    const float* gm   = (const float*)d_in[6];
    const float* bt   = (const float*)d_in[7];
    const float* mn   = (const float*)d_in[8];
    const float* vr   = (const float*)d_in[9];
    const float* xw   = (const float*)d_in[10];  // (6,64,1024)
    const float* dtw  = (const float*)d_in[11];  // (6,1024,32)
    const float* dtb  = (const float*)d_in[12];
    const float* alog = (const float*)d_in[13];  // (6,1024,16)
    const float* Dp   = (const float*)d_in[14];
    const float* lng  = (const float*)d_in[15];
    const float* lnb  = (const float*)d_in[16];
    const float* wout = (const float*)d_in[17];  // (512,1024)
    float* out = (float*)d_out;

    // workspace layout (bytes), total ~229 MiB
    uint8_t* p = (uint8_t*)d_ws;
    unsigned short* Abf    = (unsigned short*)p;  p += (size_t)3 * 4096 * 512 * 2;   // 12.6 MB
    unsigned short* Wbf    = (unsigned short*)p;  p += (size_t)3 * 2048 * 512 * 2;   //  6.3 MB
    unsigned short* Woutbf = (unsigned short*)p;  p += (size_t)512 * 1024 * 2;       //  1.0 MB
    unsigned short* Xwbf   = (unsigned short*)p;  p += (size_t)6 * 64 * 1024 * 2;    //  0.8 MB
    float*          xb     = (float*)p;           p += (size_t)3 * 4096 * 1024 * 4;  // 50.3 MB
    __hip_bfloat16* zbf    = (__hip_bfloat16*)p;  p += (size_t)3 * 4096 * 1024 * 2;  // 25.2 MB
    unsigned short* xcbf   = (unsigned short*)p;  p += (size_t)3 * 4096 * 1024 * 2;  // 25.2 MB
    float*          xdb    = (float*)p;           p += (size_t)6 * 4096 * 64 * 4;    //  6.3 MB
    float*          y6     = (float*)p;           p += (size_t)6 * 4096 * 1024 * 4;  // 100.7 MB
    // reuse xb (fp32 x dead after k_conv): deltaT f16 [6,32,1024,128] = 50.3 MB
    unsigned short* deltaT = (unsigned short*)xb;
    // reuse xb front again after scan: yg bf16 (3,32,128,1024) = 25.2 MB
    __hip_bfloat16* ygbf   = (__hip_bfloat16*)xb;

    // bf16 conversions
    k_cvt3<<<dim3(2048, 1, 3), 256, 0, stream>>>(rr, nn, tt, Abf, 4096 * 512 / 4);
    k_cvt<<<dim3(2048), 256, 0, stream>>>(wip,  Wbf, 3 * 2048 * 512 / 4);
    k_cvt<<<dim3(512),  256, 0, stream>>>(wout, Woutbf, 512 * 1024 / 4);
    k_cvt<<<dim3(384),  256, 0, stream>>>(xw,   Xwbf, 6 * 64 * 1024 / 4);

    k_gemm_inproj<<<dim3(32, 16, 3), 256, 0, stream>>>(Abf, Wbf, xb, zbf);
    k_conv<<<dim3(128, 32, 3), 256, 0, stream>>>(xb, cw, cb, gm, bt, mn, vr, xcbf);
    k_xproj<<<dim3(32, 1, 6), 256, 0, stream>>>(xcbf, Xwbf, xdb);
    k_delta<<<dim3(4, 32, 6), 256, 0, stream>>>(xdb, dtw, dtb, deltaT);
    k_scan<<<dim3(8, 32, 6), 256, 0, stream>>>(xcbf, xdb, deltaT, alog, Dp, y6);
    k_combine<<<dim3(128, 32, 3), 256, 0, stream>>>(y6, zbf, lng, lnb, ygbf);
    k_gemm_outproj<<<dim3(96, 4, 1), 256, 0, stream>>>(
        (const unsigned short*)ygbf, Woutbf, rr, nn, tt, out);
}

// Round 10
// 541.276 us; speedup vs baseline: 1.1207x; 1.0309x over previous
//
#include <hip/hip_runtime.h>
#include <hip/hip_bf16.h>
#include <hip/hip_fp16.h>
#include <math.h>

// Problem constants
#define NB 32     // batch
#define NN 128    // sequence (= 16 x 8)
#define ND 512    // model dim
#define NDI 1024  // inner dim
#define NDS 16    // state dim
#define NDR 32    // dt rank

#define L2E 1.442695040888963f   // log2(e)
#define LN2 0.6931471805599453f  // ln(2)

// raw HW transcendentals (v_exp_f32 / v_log_f32), no OCML fixup code
#define EXP2(x) __builtin_amdgcn_exp2f(x)
#define LOG2(x) __builtin_amdgcn_logf(x)

typedef __attribute__((ext_vector_type(8))) __bf16 bf16x8;
typedef __attribute__((ext_vector_type(4))) float f32x4;

typedef __attribute__((address_space(3))) void lds_void;
typedef const __attribute__((address_space(1))) void glob_void;

__device__ __forceinline__ void gload16(const void* g, void* l) {
    __builtin_amdgcn_global_load_lds((glob_void*)g, (lds_void*)l, 16, 0, 0);
}

__device__ __forceinline__ unsigned short f2bf(float x) {
    __hip_bfloat16 h = __float2bfloat16(x);
    return *(unsigned short*)&h;
}
__device__ __forceinline__ float bf2f(unsigned short v) {
    return __uint_as_float(((unsigned int)v) << 16);
}
__device__ __forceinline__ float hf2f(unsigned short v) {
    __half h = *(__half*)&v;
    return __half2float(h);
}
// sigmoid via raw exp2
__device__ __forceinline__ float sigm(float x) {
    return 1.f / (1.f + EXP2(-x * L2E));
}

// full-rate DPP pair-sum: adds value from the xor-1 lane (quad_perm [1,0,3,2])
__device__ __forceinline__ float pair_sum(float y) {
    const int sw = __builtin_amdgcn_mov_dpp(__float_as_int(y), 0xB1, 0xF, 0xF, true);
    return y + __int_as_float(sw);
}

// ---------------------------------------------------------------------------
// K0: fp32 -> bf16 conversion (RTNE). k_cvt3 handles r,n,t in one launch.
// ---------------------------------------------------------------------------
__global__ __launch_bounds__(256) void k_cvt(
    const float* __restrict__ s, unsigned short* __restrict__ d, int n4)
{
    for (int i = blockIdx.x * 256 + threadIdx.x; i < n4; i += gridDim.x * 256) {
        const float4 v = ((const float4*)s)[i];
        ushort4 o;
        o.x = f2bf(v.x); o.y = f2bf(v.y); o.z = f2bf(v.z); o.w = f2bf(v.w);
        ((ushort4*)d)[i] = o;
    }
}

__global__ __launch_bounds__(256) void k_cvt3(
    const float* __restrict__ rr, const float* __restrict__ nn,
    const float* __restrict__ tt, unsigned short* __restrict__ d, int n4)
{
    const int z = blockIdx.z;
    const float* __restrict__ s = (z == 0) ? rr : (z == 1) ? nn : tt;
    unsigned short* __restrict__ dz = d + (size_t)z * n4 * 4;
    for (int i = blockIdx.x * 256 + threadIdx.x; i < n4; i += gridDim.x * 256) {
        const float4 v = ((const float4*)s)[i];
        ushort4 o;
        o.x = f2bf(v.x); o.y = f2bf(v.y); o.z = f2bf(v.z); o.w = f2bf(v.w);
        ((ushort4*)dz)[i] = o;
    }
}

// ---------------------------------------------------------------------------
// K1: in_proj as bf16 MFMA GEMM (m97 structure). Tile 128x128, BK=32.
// ---------------------------------------------------------------------------
__global__ __launch_bounds__(256) void k_gemm_inproj(
    const unsigned short* __restrict__ Abf,
    const unsigned short* __restrict__ Wbf,
    float* __restrict__ xb, __hip_bfloat16* __restrict__ zbf)
{
    const int m = blockIdx.z;
    const int row0 = blockIdx.x * 128;
    const int col0 = blockIdx.y * 128;
    const unsigned short* __restrict__ A = Abf + (size_t)m * 4096 * 512;
    const unsigned short* __restrict__ Bw = Wbf + (size_t)m * 2048 * 512;
    const int K = 512;
    const int NT = K / 32;

    const int tid = threadIdx.x;
    const int lane = tid & 63;
    const int wave = tid >> 6;
    const int wr = wave >> 1, wc = wave & 1;
    const int lr16 = lane & 15;
    const int kk8 = (lane >> 4) << 3;

    __shared__ __align__(16) short sA[2][128 * 32];
    __shared__ __align__(16) short sB[2][128 * 32];

    f32x4 acc[4][4];
    #pragma unroll
    for (int i = 0; i < 4; ++i)
        #pragma unroll
        for (int j = 0; j < 4; ++j)
            acc[i][j] = (f32x4){0.f, 0.f, 0.f, 0.f};

    #define STAGE(buf, t)                                                        \
        {                                                                        \
            const int k0 = (t) * 32;                                             \
            _Pragma("unroll")                                                    \
            for (int i = 0; i < 2; ++i) {                                        \
                const int c = i * 256 + tid;                                     \
                const int rowc = c >> 2;                                         \
                const int kc = (c & 3) << 3;                                     \
                gload16(A + (size_t)(row0 + rowc) * K + k0 + kc,                 \
                        &sA[buf][rowc * 32 + kc]);                               \
                gload16(Bw + (size_t)(col0 + rowc) * K + k0 + kc,                \
                        &sB[buf][rowc * 32 + kc]);                               \
            }                                                                    \
        }

    #define COMPUTE(buf)                                                         \
        {                                                                        \
            bf16x8 af[4], bfr[4];                                                \
            _Pragma("unroll")                                                    \
            for (int i = 0; i < 4; ++i) {                                        \
                af[i]  = *(const bf16x8*)&sA[buf][(wr * 64 + i * 16 + lr16) * 32 + kk8]; \
                bfr[i] = *(const bf16x8*)&sB[buf][(wc * 64 + i * 16 + lr16) * 32 + kk8]; \
            }                                                                    \
            _Pragma("unroll")                                                    \
            for (int i = 0; i < 4; ++i)                                          \
                _Pragma("unroll")                                                \
                for (int j = 0; j < 4; ++j)                                      \
                    acc[i][j] = __builtin_amdgcn_mfma_f32_16x16x32_bf16(         \
                        af[i], bfr[j], acc[i][j], 0, 0, 0);                      \
        }

    STAGE(0, 0);
    __syncthreads();
    int cur = 0;
    for (int t = 0; t < NT - 1; ++t) {
        STAGE(cur ^ 1, t + 1);
        COMPUTE(cur);
        __syncthreads();
        cur ^= 1;
    }
    COMPUTE(cur);

    const bool isX = (col0 < 1024);
    #pragma unroll
    for (int i = 0; i < 4; ++i) {
        const int rb = row0 + wr * 64 + i * 16 + ((lane >> 4) << 2);
        #pragma unroll
        for (int j = 0; j < 4; ++j) {
            const int cc = col0 + wc * 64 + j * 16 + lr16;
            #pragma unroll
            for (int r = 0; r < 4; ++r) {
                const float v = acc[i][j][r];
                const int row = rb + r;
                if (isX)
                    xb[((size_t)m * 4096 + row) * 1024 + cc] = v;
                else
                    zbf[((size_t)m * 4096 + row) * 1024 + (cc - 1024)] =
                        __float2bfloat16(v);
            }
        }
    }
    #undef STAGE
    #undef COMPUTE
}

// ---------------------------------------------------------------------------
// K2: depthwise 3x3 conv (SAME) + bias + BN + SiLU -> bf16 output.
// ---------------------------------------------------------------------------
__global__ __launch_bounds__(256) void k_conv(
    const float* __restrict__ x, const float* __restrict__ cw,
    const float* __restrict__ cb, const float* __restrict__ gm,
    const float* __restrict__ bt, const float* __restrict__ mn,
    const float* __restrict__ vr, unsigned short* __restrict__ out)
{
    const int nIdx = blockIdx.x;       // 0..127
    const int b = blockIdx.y;
    const int m = blockIdx.z;
    const int h = nIdx >> 3, w = nIdx & 7;
    const float* __restrict__ xm = x + ((size_t)(m * NB + b)) * NN * NDI;

    #pragma unroll
    for (int q = 0; q < 4; ++q) {
        const int di = (q << 8) + threadIdx.x;
        const float* __restrict__ wp = cw + ((size_t)(m * NDI + di)) * 9;
        float s = 0.f;
        #pragma unroll
        for (int kh = 0; kh < 3; ++kh) {
            const int hh = h + kh - 1;
            if ((unsigned)hh < 16u) {
                #pragma unroll
                for (int kw = 0; kw < 3; ++kw) {
                    const int ww = w + kw - 1;
                    if ((unsigned)ww < 8u)
                        s = fmaf(xm[(size_t)(hh * 8 + ww) * NDI + di],
                                 wp[kh * 3 + kw], s);
                }
            }
        }
        const int c = m * NDI + di;
        const float scale = gm[c] * rsqrtf(vr[c] + 1e-5f);
        const float y = (s + cb[c] - mn[c]) * scale + bt[c];
        out[((size_t)(m * NB + b) * NN + nIdx) * NDI + di] = f2bf(y * sigm(y));
    }
}

// ---------------------------------------------------------------------------
// K3: xproj as bf16 MFMA GEMM. A = xcbf [3][4096][1024] (row remap for rev),
// B = xwbf [6][64][1024]. C = xd fp32 [6][4096][64]. Tile 128x64, BK=32.
// ---------------------------------------------------------------------------
__global__ __launch_bounds__(256) void k_xproj(
    const unsigned short* __restrict__ xcbf,
    const unsigned short* __restrict__ xwbf,
    float* __restrict__ xd)
{
    const int s = blockIdx.z;
    const int m = (s >= 3) ? (s - 3) : s;
    const bool rev = s >= 3;
    const unsigned short* __restrict__ A = xcbf + (size_t)m * 4096 * 1024;
    const unsigned short* __restrict__ Bw = xwbf + (size_t)s * 64 * 1024;
    const int row0 = blockIdx.x * 128;
    const int NT = 32;  // K=1024 / 32

    const int tid = threadIdx.x;
    const int lane = tid & 63;
    const int wave = tid >> 6;
    const int wr = wave >> 1, wc = wave & 1;
    const int lr16 = lane & 15;
    const int kk8 = (lane >> 4) << 3;

    __shared__ __align__(16) short sA[2][128 * 32];
    __shared__ __align__(16) short sB[2][64 * 32];

    f32x4 acc[4][2];
    #pragma unroll
    for (int i = 0; i < 4; ++i)
        #pragma unroll
        for (int j = 0; j < 2; ++j)
            acc[i][j] = (f32x4){0.f, 0.f, 0.f, 0.f};

    #define STAGEX(buf, t)                                                       \
        {                                                                        \
            const int k0 = (t) * 32;                                             \
            _Pragma("unroll")                                                    \
            for (int i = 0; i < 2; ++i) {                                        \
                const int c = i * 256 + tid;                                     \
                const int rowc = c >> 2;                                         \
                const int kc = (c & 3) << 3;                                     \
                const int arow = row0 + rowc;                                    \
                const int ab = arow >> 7, at = arow & 127;                       \
                const int srow = ab * NN + (rev ? (NN - 1 - at) : at);           \
                gload16(A + (size_t)srow * 1024 + k0 + kc,                       \
                        &sA[buf][rowc * 32 + kc]);                               \
            }                                                                    \
            {                                                                    \
                const int rowc = tid >> 2;                                       \
                const int kc = (tid & 3) << 3;                                   \
                gload16(Bw + (size_t)rowc * 1024 + k0 + kc,                      \
                        &sB[buf][rowc * 32 + kc]);                               \
            }                                                                    \
        }

    #define COMPUTEX(buf)                                                        \
        {                                                                        \
            bf16x8 af[4], bfr[2];                                                \
            _Pragma("unroll")                                                    \
            for (int i = 0; i < 4; ++i)                                          \
                af[i] = *(const bf16x8*)&sA[buf][(wr * 64 + i * 16 + lr16) * 32 + kk8]; \
            _Pragma("unroll")                                                    \
            for (int j = 0; j < 2; ++j)                                          \
                bfr[j] = *(const bf16x8*)&sB[buf][(wc * 32 + j * 16 + lr16) * 32 + kk8]; \
            _Pragma("unroll")                                                    \
            for (int i = 0; i < 4; ++i)                                          \
                _Pragma("unroll")                                                \
                for (int j = 0; j < 2; ++j)                                      \
                    acc[i][j] = __builtin_amdgcn_mfma_f32_16x16x32_bf16(         \
                        af[i], bfr[j], acc[i][j], 0, 0, 0);                      \
        }

    STAGEX(0, 0);
    __syncthreads();
    int cur = 0;
    for (int t = 0; t < NT - 1; ++t) {
        STAGEX(cur ^ 1, t + 1);
        COMPUTEX(cur);
        __syncthreads();
        cur ^= 1;
    }
    COMPUTEX(cur);

    #pragma unroll
    for (int i = 0; i < 4; ++i) {
        const int rb = row0 + wr * 64 + i * 16 + ((lane >> 4) << 2);
        #pragma unroll
        for (int j = 0; j < 2; ++j) {
            const int cc = wc * 32 + j * 16 + lr16;
            #pragma unroll
            for (int r = 0; r < 4; ++r) {
                const int row = rb + r;
                xd[((size_t)s * 4096 + row) * 64 + cc] = acc[i][j][r];
            }
        }
    }
    #undef STAGEX
    #undef COMPUTEX
}

// ---------------------------------------------------------------------------
// K3b: delta precompute, TRANSPOSED f16 output [s,b,d,t] so the scan can
// load 8 steps per 16B. Softplus via raw v_exp/v_log.
// ---------------------------------------------------------------------------
__global__ __launch_bounds__(256) void k_delta(
    const float* __restrict__ xd, const float* __restrict__ dtw,
    const float* __restrict__ dtb, unsigned short* __restrict__ deltaT)
{
    const int s = blockIdx.z, b = blockIdx.y;
    const int d = blockIdx.x * 256 + threadIdx.x;

    float wdt[NDR];
    const float* __restrict__ wp = dtw + ((size_t)s * NDI + d) * NDR;
    #pragma unroll
    for (int r = 0; r < NDR; r += 4)
        *(float4*)&wdt[r] = *(const float4*)(wp + r);
    const float bias = dtb[s * NDI + d];

    const float* __restrict__ xrow = xd + ((size_t)(s * NB + b)) * NN * 64;
    unsigned short* __restrict__ dout =
        deltaT + (((size_t)(s * NB + b)) * NDI + d) * NN;

    for (int t8 = 0; t8 < NN / 8; ++t8) {
        ushort4 o0, o1;
        unsigned short* op0 = (unsigned short*)&o0;
        unsigned short* op1 = (unsigned short*)&o1;
        #pragma unroll
        for (int k = 0; k < 8; ++k) {
            const int t = t8 * 8 + k;
            const float* __restrict__ xr = xrow + (size_t)t * 64;  // uniform
            float dl = bias;
            #pragma unroll
            for (int q = 0; q < 8; ++q) {
                const float4 v = *(const float4*)(xr + q * 4);
                dl = fmaf(v.x, wdt[q * 4 + 0], dl);
                dl = fmaf(v.y, wdt[q * 4 + 1], dl);
                dl = fmaf(v.z, wdt[q * 4 + 2], dl);
                dl = fmaf(v.w, wdt[q * 4 + 3], dl);
            }
            // stable softplus: max(x,0) + ln(1 + 2^(-|x|*L2E))
            const float e = EXP2(-fabsf(dl) * L2E);
            const float dlt = fmaxf(dl, 0.f) + LOG2(1.f + e) * LN2;
            const __half hv = __float2half(dlt);
            if (k < 4) op0[k] = *(const unsigned short*)&hv;
            else       op1[k - 4] = *(const unsigned short*)&hv;
        }
        *(ushort4*)(dout + t8 * 8) = o0;
        *(ushort4*)(dout + t8 * 8 + 4) = o1;
    }
}

// ---------------------------------------------------------------------------
// K4: selective scan v6: state-split lane pairs + software pipeline +
// raw v_exp_f32 transcendentals (no OCML fixup).
// ---------------------------------------------------------------------------
__global__ __launch_bounds__(256) void k_scan(
    const unsigned short* __restrict__ xcbf, const float* __restrict__ xd,
    const unsigned short* __restrict__ deltaT,
    const float* __restrict__ alog, const float* __restrict__ Dp,
    float* __restrict__ y6)
{
    const int s = blockIdx.z, b = blockIdx.y;
    const int tid = threadIdx.x;
    const int jg = tid & 1;                       // state half
    const int d = blockIdx.x * 128 + (tid >> 1);  // channel
    const int m = (s >= 3) ? (s - 3) : s;
    const bool rev = s >= 3;

    float a2[8], h[8];
    const float* __restrict__ ap = alog + ((size_t)s * NDI + d) * NDS + jg * 8;
    #pragma unroll
    for (int j = 0; j < 8; j += 4) {
        const float4 v = *(const float4*)(ap + j);
        // a2 = -exp(A_log)*log2(e) = -exp2(A_log*L2E)*L2E
        a2[j]     = -EXP2(v.x * L2E) * L2E;
        a2[j + 1] = -EXP2(v.y * L2E) * L2E;
        a2[j + 2] = -EXP2(v.z * L2E) * L2E;
        a2[j + 3] = -EXP2(v.w * L2E) * L2E;
        h[j] = h[j + 1] = h[j + 2] = h[j + 3] = 0.f;
    }
    const float Dd = Dp[s * NDI + d];

    const unsigned short* __restrict__ up =
        xcbf + ((size_t)(m * NB + b)) * NN * NDI + d;
    const float* __restrict__ xr =
        xd + ((size_t)(s * NB + b)) * NN * 64 + 32 + jg * 8;
    const unsigned short* __restrict__ dpT =
        deltaT + (((size_t)(s * NB + b)) * NDI + d) * NN;
    float* __restrict__ yp = y6 + ((size_t)(s * NB + b)) * NN * NDI + d;

    int un = (rev ? (NN - 1) : 0) * NDI;
    const int ustep = rev ? -NDI : NDI;
    const bool writer = (jg == 0);

    // prologue: t=0 inputs + first two delta groups
    uint4 dv  = *(const uint4*)dpT;
    uint4 dvn = *(const uint4*)(dpT + 8);
    float u = bf2f(up[un]); un += ustep;
    float4 B0 = *(const float4*)(xr);
    float4 B1 = *(const float4*)(xr + 4);
    float4 C0 = *(const float4*)(xr + 16);
    float4 C1 = *(const float4*)(xr + 20);

    for (int t8 = 0; t8 < NN / 8; ++t8) {
        #pragma unroll
        for (int k = 0; k < 8; ++k) {
            // prefetch step t+1 (reads ≤256B past slab end on final step; ws-safe)
            const float* __restrict__ xn = xr + 64;
            const float4 nB0 = *(const float4*)(xn);
            const float4 nB1 = *(const float4*)(xn + 4);
            const float4 nC0 = *(const float4*)(xn + 16);
            const float4 nC1 = *(const float4*)(xn + 20);
            const float u_n = bf2f(up[un]); un += ustep;

            const float delta = hf2f(((const unsigned short*)&dv)[k]);
            const float du = delta * u;
            float y = 0.f;
            #pragma unroll
            for (int j = 0; j < 4; ++j) {
                const float dA = EXP2(delta * a2[j]);
                h[j] = fmaf(dA, h[j], du * ((const float*)&B0)[j]);
                y = fmaf(h[j], ((const float*)&C0)[j], y);
            }
            #pragma unroll
            for (int j = 0; j < 4; ++j) {
                const float dA = EXP2(delta * a2[4 + j]);
                h[4 + j] = fmaf(dA, h[4 + j], du * ((const float*)&B1)[j]);
                y = fmaf(h[4 + j], ((const float*)&C1)[j], y);
            }
            y = pair_sum(y);
            if (writer) yp[(size_t)(t8 * 8 + k) * NDI] = fmaf(u, Dd, y);

            u = u_n; B0 = nB0; B1 = nB1; C0 = nC0; C1 = nC1; xr = xn;
        }
        dv = dvn;
        dvn = *(const uint4*)(dpT + (t8 + 2) * 8);  // reads past only at the tail; ws-safe
    }
}

// ---------------------------------------------------------------------------
// K5: LN + fwd/rev combine + SiLU(z) gating, float4-vectorized.
// ---------------------------------------------------------------------------
__global__ __launch_bounds__(256) void k_combine(
    const float* __restrict__ y6, const __hip_bfloat16* __restrict__ zbf,
    const float* __restrict__ g, const float* __restrict__ be,
    __hip_bfloat16* __restrict__ yg)
{
    const int t = blockIdx.x, b = blockIdx.y, m = blockIdx.z;
    const int tid = threadIdx.x;
    const int dd = tid << 2;
    const float* __restrict__ rowf = y6 + ((size_t)(m * NB + b) * NN + t) * NDI;
    const float* __restrict__ rowr =
        y6 + ((size_t)((m + 3) * NB + b) * NN + (NN - 1 - t)) * NDI;
    const __hip_bfloat16* __restrict__ zrow =
        zbf + ((size_t)(m * NB + b) * NN + t) * NDI;

    const float4 vf = *(const float4*)(rowf + dd);
    const float4 vr = *(const float4*)(rowr + dd);
    float sf = vf.x + vf.y + vf.z + vf.w;
    float qf = vf.x * vf.x + vf.y * vf.y + vf.z * vf.z + vf.w * vf.w;
    float sr = vr.x + vr.y + vr.z + vr.w;
    float qr = vr.x * vr.x + vr.y * vr.y + vr.z * vr.z + vr.w * vr.w;

    #pragma unroll
    for (int off = 32; off > 0; off >>= 1) {
        sf += __shfl_down(sf, off, 64);
        qf += __shfl_down(qf, off, 64);
        sr += __shfl_down(sr, off, 64);
        qr += __shfl_down(qr, off, 64);
    }
    __shared__ float red[4][4];
    const int wv = tid >> 6;
    if ((tid & 63) == 0) { red[wv][0] = sf; red[wv][1] = qf; red[wv][2] = sr; red[wv][3] = qr; }
    __syncthreads();
    const float tsf = red[0][0] + red[1][0] + red[2][0] + red[3][0];
    const float tqf = red[0][1] + red[1][1] + red[2][1] + red[3][1];
    const float tsr = red[0][2] + red[1][2] + red[2][2] + red[3][2];
    const float tqr = red[0][3] + red[1][3] + red[2][3] + red[3][3];
    const float muf = tsf * (1.f / NDI);
    const float varf = tqf * (1.f / NDI) - muf * muf;
    const float rsf = rsqrtf(varf + 1e-5f);
    const float mur = tsr * (1.f / NDI);
    const float varr = tqr * (1.f / NDI) - mur * mur;
    const float rsr = rsqrtf(varr + 1e-5f);

    const float4 gf = *(const float4*)(g + m * NDI + dd);
    const float4 bf = *(const float4*)(be + m * NDI + dd);
    const float4 gr = *(const float4*)(g + (m + 3) * NDI + dd);
    const float4 br = *(const float4*)(be + (m + 3) * NDI + dd);
    const ushort4 zu = *(const ushort4*)(zrow + dd);

    float lf[4], lr2[4], zv[4];
    lf[0] = (vf.x - muf) * rsf * gf.x + bf.x;
    lf[1] = (vf.y - muf) * rsf * gf.y + bf.y;
    lf[2] = (vf.z - muf) * rsf * gf.z + bf.z;
    lf[3] = (vf.w - muf) * rsf * gf.w + bf.w;
    lr2[0] = (vr.x - mur) * rsr * gr.x + br.x;
    lr2[1] = (vr.y - mur) * rsr * gr.y + br.y;
    lr2[2] = (vr.z - mur) * rsr * gr.z + br.z;
    lr2[3] = (vr.w - mur) * rsr * gr.w + br.w;
    zv[0] = bf2f(zu.x);
    zv[1] = bf2f(zu.y);
    zv[2] = bf2f(zu.z);
    zv[3] = bf2f(zu.w);

    ushort4 o;
    unsigned short* op = (unsigned short*)&o;
    #pragma unroll
    for (int q = 0; q < 4; ++q) {
        op[q] = f2bf((lf[q] + lr2[q]) * zv[q] * sigm(zv[q]));
    }
    *(ushort4*)(yg + ((size_t)(m * NB + b) * NN + t) * NDI + dd) = o;
}

// ---------------------------------------------------------------------------
// K6: out_proj as bf16 MFMA GEMM + fp32 residual add.
// ---------------------------------------------------------------------------
__global__ __launch_bounds__(256) void k_gemm_outproj(
    const unsigned short* __restrict__ Abf,
    const unsigned short* __restrict__ Wbf,
    const float* __restrict__ rr, const float* __restrict__ nn,
    const float* __restrict__ tt, float* __restrict__ out)
{
    const int row0 = blockIdx.x * 128;   // over 12288
    const int col0 = blockIdx.y * 128;   // over 512
    const int K = 1024;
    const int NT = K / 32;

    const int tid = threadIdx.x;
    const int lane = tid & 63;
    const int wave = tid >> 6;
    const int wr = wave >> 1, wc = wave & 1;
    const int lr16 = lane & 15;
    const int kk8 = (lane >> 4) << 3;

    __shared__ __align__(16) short sA[2][128 * 32];
    __shared__ __align__(16) short sB[2][128 * 32];

    f32x4 acc[4][4];
    #pragma unroll
    for (int i = 0; i < 4; ++i)
        #pragma unroll
        for (int j = 0; j < 4; ++j)
            acc[i][j] = (f32x4){0.f, 0.f, 0.f, 0.f};

    #define STAGE(buf, t)                                                        \
        {                                                                        \
            const int k0 = (t) * 32;                                             \
            _Pragma("unroll")                                                    \
            for (int i = 0; i < 2; ++i) {                                        \
                const int c = i * 256 + tid;                                     \
                const int rowc = c >> 2;                                         \
                const int kc = (c & 3) << 3;                                     \
                gload16(Abf + (size_t)(row0 + rowc) * K + k0 + kc,               \
                        &sA[buf][rowc * 32 + kc]);                               \
                gload16(Wbf + (size_t)(col0 + rowc) * K + k0 + kc,               \
                        &sB[buf][rowc * 32 + kc]);                               \
            }                                                                    \
        }

    #define COMPUTE(buf)                                                         \
        {                                                                        \
            bf16x8 af[4], bfr[4];                                                \
            _Pragma("unroll")                                                    \
            for (int i = 0; i < 4; ++i) {                                        \
                af[i]  = *(const bf16x8*)&sA[buf][(wr * 64 + i * 16 + lr16) * 32 + kk8]; \
                bfr[i] = *(const bf16x8*)&sB[buf][(wc * 64 + i * 16 + lr16) * 32 + kk8]; \
            }                                                                    \
            _Pragma("unroll")                                                    \
            for (int i = 0; i < 4; ++i)                                          \
                _Pragma("unroll")                                                \
                for (int j = 0; j < 4; ++j)                                      \
                    acc[i][j] = __builtin_amdgcn_mfma_f32_16x16x32_bf16(         \
                        af[i], bfr[j], acc[i][j], 0, 0, 0);                      \
        }

    STAGE(0, 0);
    __syncthreads();
    int cur = 0;
    for (int t = 0; t < NT - 1; ++t) {
        STAGE(cur ^ 1, t + 1);
        COMPUTE(cur);
        __syncthreads();
        cur ^= 1;
    }
    COMPUTE(cur);

    const int m = row0 >> 12;  // uniform per block (128 | 4096)
    const float* __restrict__ resid = (m == 0) ? rr : (m == 1) ? nn : tt;
    #pragma unroll
    for (int i = 0; i < 4; ++i) {
        const int rb = row0 + wr * 64 + i * 16 + ((lane >> 4) << 2);
        #pragma unroll
        for (int j = 0; j < 4; ++j) {
            const int cc = col0 + wc * 64 + j * 16 + lr16;
            #pragma unroll
            for (int r = 0; r < 4; ++r) {
                const int row = rb + r;
                const int bt = row & 4095;
                out[(size_t)row * ND + cc] =
                    acc[i][j][r] + resid[(size_t)bt * ND + cc];
            }
        }
    }
    #undef STAGE
    #undef COMPUTE
}

// ---------------------------------------------------------------------------
extern "C" void kernel_launch(void* const* d_in, const int* in_sizes, int n_in,
                              void* d_out, int out_size, void* d_ws, size_t ws_size,
                              hipStream_t stream) {
    const float* rr   = (const float*)d_in[0];
    const float* nn   = (const float*)d_in[1];
    const float* tt   = (const float*)d_in[2];
    const float* wip  = (const float*)d_in[3];   // (3,2048,512)
    const float* cw   = (const float*)d_in[4];   // (3,1024,1,3,3)
    const float* cb   = (const float*)d_in[5];
    const float* gm   = (const float*)d_in[6];
    const float* bt   = (const float*)d_in[7];
    const float* mn   = (const float*)d_in[8];
    const float* vr   = (const float*)d_in[9];
    const float* xw   = (const float*)d_in[10];  // (6,64,1024)
    const float* dtw  = (const float*)d_in[11];  // (6,1024,32)
    const float* dtb  = (const float*)d_in[12];
    const float* alog = (const float*)d_in[13];  // (6,1024,16)
    const float* Dp   = (const float*)d_in[14];
    const float* lng  = (const float*)d_in[15];
    const float* lnb  = (const float*)d_in[16];
    const float* wout = (const float*)d_in[17];  // (512,1024)
    float* out = (float*)d_out;

    // workspace layout (bytes), total ~229 MiB
    uint8_t* p = (uint8_t*)d_ws;
    unsigned short* Abf    = (unsigned short*)p;  p += (size_t)3 * 4096 * 512 * 2;   // 12.6 MB
    unsigned short* Wbf    = (unsigned short*)p;  p += (size_t)3 * 2048 * 512 * 2;   //  6.3 MB
    unsigned short* Woutbf = (unsigned short*)p;  p += (size_t)512 * 1024 * 2;       //  1.0 MB
    unsigned short* Xwbf   = (unsigned short*)p;  p += (size_t)6 * 64 * 1024 * 2;    //  0.8 MB
    float*          xb     = (float*)p;           p += (size_t)3 * 4096 * 1024 * 4;  // 50.3 MB
    __hip_bfloat16* zbf    = (__hip_bfloat16*)p;  p += (size_t)3 * 4096 * 1024 * 2;  // 25.2 MB
    unsigned short* xcbf   = (unsigned short*)p;  p += (size_t)3 * 4096 * 1024 * 2;  // 25.2 MB
    float*          xdb    = (float*)p;           p += (size_t)6 * 4096 * 64 * 4;    //  6.3 MB
    float*          y6     = (float*)p;           p += (size_t)6 * 4096 * 1024 * 4;  // 100.7 MB
    // reuse xb (fp32 x dead after k_conv): deltaT f16 [6,32,1024,128] = 50.3 MB
    unsigned short* deltaT = (unsigned short*)xb;
    // reuse xb front again after scan: yg bf16 (3,32,128,1024) = 25.2 MB
    __hip_bfloat16* ygbf   = (__hip_bfloat16*)xb;

    // bf16 conversions
    k_cvt3<<<dim3(2048, 1, 3), 256, 0, stream>>>(rr, nn, tt, Abf, 4096 * 512 / 4);
    k_cvt<<<dim3(2048), 256, 0, stream>>>(wip,  Wbf, 3 * 2048 * 512 / 4);
    k_cvt<<<dim3(512),  256, 0, stream>>>(wout, Woutbf, 512 * 1024 / 4);
    k_cvt<<<dim3(384),  256, 0, stream>>>(xw,   Xwbf, 6 * 64 * 1024 / 4);

    k_gemm_inproj<<<dim3(32, 16, 3), 256, 0, stream>>>(Abf, Wbf, xb, zbf);
    k_conv<<<dim3(128, 32, 3), 256, 0, stream>>>(xb, cw, cb, gm, bt, mn, vr, xcbf);
    k_xproj<<<dim3(32, 1, 6), 256, 0, stream>>>(xcbf, Xwbf, xdb);
    k_delta<<<dim3(4, 32, 6), 256, 0, stream>>>(xdb, dtw, dtb, deltaT);
    k_scan<<<dim3(8, 32, 6), 256, 0, stream>>>(xcbf, xdb, deltaT, alog, Dp, y6);
    k_combine<<<dim3(128, 32, 3), 256, 0, stream>>>(y6, zbf, lng, lnb, ygbf);
    k_gemm_outproj<<<dim3(96, 4, 1), 256, 0, stream>>>(
        (const unsigned short*)ygbf, Woutbf, rr, nn, tt, out);
}

// Round 12
// 436.951 us; speedup vs baseline: 1.3883x; 1.2388x over previous
//
#include <hip/hip_runtime.h>
#include <hip/hip_bf16.h>
#include <hip/hip_fp16.h>
#include <math.h>

// Problem constants
#define NB 32     // batch
#define NN 128    // sequence (= 16 x 8)
#define ND 512    // model dim
#define NDI 1024  // inner dim
#define NDS 16    // state dim
#define NDR 32    // dt rank

#define L2E 1.442695040888963f   // log2(e)
#define LN2 0.6931471805599453f  // ln(2)

// raw HW transcendentals (v_exp_f32 / v_log_f32), no OCML fixup code
#define EXP2(x) __builtin_amdgcn_exp2f(x)
#define LOG2(x) __builtin_amdgcn_logf(x)

typedef __attribute__((ext_vector_type(8))) __bf16 bf16x8;
typedef __attribute__((ext_vector_type(4))) float f32x4;

typedef __attribute__((address_space(3))) void lds_void;
typedef const __attribute__((address_space(1))) void glob_void;

__device__ __forceinline__ void gload16(const void* g, void* l) {
    __builtin_amdgcn_global_load_lds((glob_void*)g, (lds_void*)l, 16, 0, 0);
}

__device__ __forceinline__ unsigned short f2bf(float x) {
    __hip_bfloat16 h = __float2bfloat16(x);
    return *(unsigned short*)&h;
}
__device__ __forceinline__ float bf2f(unsigned short v) {
    return __uint_as_float(((unsigned int)v) << 16);
}
__device__ __forceinline__ float hf2f(unsigned short v) {
    __half h = *(__half*)&v;
    return __half2float(h);
}
__device__ __forceinline__ unsigned short f2hf(float x) {
    __half h = __float2half(x);
    return *(unsigned short*)&h;
}
// sigmoid via raw exp2
__device__ __forceinline__ float sigm(float x) {
    return 1.f / (1.f + EXP2(-x * L2E));
}

// full-rate DPP pair-sum: adds value from the xor-1 lane (quad_perm [1,0,3,2])
__device__ __forceinline__ float pair_sum(float y) {
    const int sw = __builtin_amdgcn_mov_dpp(__float_as_int(y), 0xB1, 0xF, 0xF, true);
    return y + __int_as_float(sw);
}

// ---------------------------------------------------------------------------
// K0: fp32 -> bf16 conversion (RTNE). k_cvt3 handles r,n,t in one launch.
// ---------------------------------------------------------------------------
__global__ __launch_bounds__(256) void k_cvt(
    const float* __restrict__ s, unsigned short* __restrict__ d, int n4)
{
    for (int i = blockIdx.x * 256 + threadIdx.x; i < n4; i += gridDim.x * 256) {
        const float4 v = ((const float4*)s)[i];
        ushort4 o;
        o.x = f2bf(v.x); o.y = f2bf(v.y); o.z = f2bf(v.z); o.w = f2bf(v.w);
        ((ushort4*)d)[i] = o;
    }
}

__global__ __launch_bounds__(256) void k_cvt3(
    const float* __restrict__ rr, const float* __restrict__ nn,
    const float* __restrict__ tt, unsigned short* __restrict__ d, int n4)
{
    const int z = blockIdx.z;
    const float* __restrict__ s = (z == 0) ? rr : (z == 1) ? nn : tt;
    unsigned short* __restrict__ dz = d + (size_t)z * n4 * 4;
    for (int i = blockIdx.x * 256 + threadIdx.x; i < n4; i += gridDim.x * 256) {
        const float4 v = ((const float4*)s)[i];
        ushort4 o;
        o.x = f2bf(v.x); o.y = f2bf(v.y); o.z = f2bf(v.z); o.w = f2bf(v.w);
        ((ushort4*)dz)[i] = o;
    }
}

// ---------------------------------------------------------------------------
// K1: in_proj bf16 MFMA GEMM with FUSED depthwise conv + BN + SiLU epilogue.
// Tile 128x128, BK=32. A 128-row tile == one batch image (all 128 t of one b),
// and the conv is depthwise, so after the K-loop the (dead) sA/sB LDS is
// re-aliased as a f16 [128][128] spatial tile (XOR-swizzled: c^((t&31)<<1)
// keeps ds_read_u16 at <=2 lanes/bank) and each thread convolves its own 64
// (t,c) positions. x-path writes xcbf bf16 directly; z-path writes zbf.
// ---------------------------------------------------------------------------
__global__ __launch_bounds__(256) void k_gemm_inproj_conv(
    const unsigned short* __restrict__ Abf,
    const unsigned short* __restrict__ Wbf,
    const float* __restrict__ cw, const float* __restrict__ cbb,
    const float* __restrict__ gm, const float* __restrict__ bt,
    const float* __restrict__ mn, const float* __restrict__ vr,
    unsigned short* __restrict__ xcbf, __hip_bfloat16* __restrict__ zbf)
{
    const int m = blockIdx.z;
    const int row0 = blockIdx.x * 128;
    const int col0 = blockIdx.y * 128;
    const unsigned short* __restrict__ A = Abf + (size_t)m * 4096 * 512;
    const unsigned short* __restrict__ Bw = Wbf + (size_t)m * 2048 * 512;
    const int K = 512;
    const int NT = K / 32;

    const int tid = threadIdx.x;
    const int lane = tid & 63;
    const int wave = tid >> 6;
    const int wr = wave >> 1, wc = wave & 1;
    const int lr16 = lane & 15;
    const int kk8 = (lane >> 4) << 3;

    // 32 KB shared: GEMM double-buffers; re-aliased as conv tile afterwards.
    __shared__ __align__(16) short smem[16384];
    short (*sA)[128 * 32] = (short(*)[128 * 32])smem;           // [0, 8192)
    short (*sB)[128 * 32] = (short(*)[128 * 32])(smem + 8192);  // [8192, 16384)

    f32x4 acc[4][4];
    #pragma unroll
    for (int i = 0; i < 4; ++i)
        #pragma unroll
        for (int j = 0; j < 4; ++j)
            acc[i][j] = (f32x4){0.f, 0.f, 0.f, 0.f};

    #define STAGE(buf, t)                                                        \
        {                                                                        \
            const int k0 = (t) * 32;                                             \
            _Pragma("unroll")                                                    \
            for (int i = 0; i < 2; ++i) {                                        \
                const int c = i * 256 + tid;                                     \
                const int rowc = c >> 2;                                         \
                const int kc = (c & 3) << 3;                                     \
                gload16(A + (size_t)(row0 + rowc) * K + k0 + kc,                 \
                        &sA[buf][rowc * 32 + kc]);                               \
                gload16(Bw + (size_t)(col0 + rowc) * K + k0 + kc,                \
                        &sB[buf][rowc * 32 + kc]);                               \
            }                                                                    \
        }

    #define COMPUTE(buf)                                                         \
        {                                                                        \
            bf16x8 af[4], bfr[4];                                                \
            _Pragma("unroll")                                                    \
            for (int i = 0; i < 4; ++i) {                                        \
                af[i]  = *(const bf16x8*)&sA[buf][(wr * 64 + i * 16 + lr16) * 32 + kk8]; \
                bfr[i] = *(const bf16x8*)&sB[buf][(wc * 64 + i * 16 + lr16) * 32 + kk8]; \
            }                                                                    \
            _Pragma("unroll")                                                    \
            for (int i = 0; i < 4; ++i)                                          \
                _Pragma("unroll")                                                \
                for (int j = 0; j < 4; ++j)                                      \
                    acc[i][j] = __builtin_amdgcn_mfma_f32_16x16x32_bf16(         \
                        af[i], bfr[j], acc[i][j], 0, 0, 0);                      \
        }

    STAGE(0, 0);
    __syncthreads();
    int cur = 0;
    for (int t = 0; t < NT - 1; ++t) {
        STAGE(cur ^ 1, t + 1);
        COMPUTE(cur);
        __syncthreads();
        cur ^= 1;
    }
    COMPUTE(cur);

    if (col0 < 1024) {
        // ---- fused conv path ----
        __syncthreads();  // all waves done reading sA/sB
        ushort* ct = (ushort*)smem;  // f16 [128][128], swizzled
        #pragma unroll
        for (int i = 0; i < 4; ++i) {
            #pragma unroll
            for (int j = 0; j < 4; ++j) {
                #pragma unroll
                for (int r = 0; r < 4; ++r) {
                    const int t = wr * 64 + i * 16 + ((lane >> 4) << 2) + r;
                    const int c = wc * 64 + j * 16 + lr16;
                    ct[t * 128 + (c ^ ((t & 31) << 1))] = f2hf(acc[i][j][r]);
                }
            }
        }
        __syncthreads();
        const int b = blockIdx.x;  // 128-row tile == one image
        unsigned short* __restrict__ orow =
            xcbf + ((size_t)(m * NB + b)) * NN * NDI + col0;
        #pragma unroll
        for (int j = 0; j < 4; ++j) {
            const int c = wc * 64 + j * 16 + lr16;
            const int cidx = m * NDI + col0 + c;
            const float* __restrict__ wp = cw + (size_t)cidx * 9;
            float w9[9];
            #pragma unroll
            for (int k = 0; k < 9; ++k) w9[k] = wp[k];
            const float scale = gm[cidx] * rsqrtf(vr[cidx] + 1e-5f);
            const float shift = (cbb[cidx] - mn[cidx]) * scale + bt[cidx];
            #pragma unroll
            for (int i = 0; i < 4; ++i) {
                #pragma unroll
                for (int r = 0; r < 4; ++r) {
                    const int t = wr * 64 + i * 16 + ((lane >> 4) << 2) + r;
                    const int h = t >> 3, w = t & 7;
                    float s = 0.f;
                    #pragma unroll
                    for (int kh = 0; kh < 3; ++kh) {
                        const int hh = h + kh - 1;
                        if ((unsigned)hh < 16u) {
                            #pragma unroll
                            for (int kw = 0; kw < 3; ++kw) {
                                const int ww = w + kw - 1;
                                if ((unsigned)ww < 8u) {
                                    const int tt = hh * 8 + ww;
                                    const unsigned short uv =
                                        ct[tt * 128 + (c ^ ((tt & 31) << 1))];
                                    s = fmaf(hf2f(uv), w9[kh * 3 + kw], s);
                                }
                            }
                        }
                    }
                    const float y = fmaf(s, scale, shift);
                    orow[(size_t)t * NDI + c] = f2bf(y * sigm(y));
                }
            }
        }
    } else {
        // ---- z path ----
        #pragma unroll
        for (int i = 0; i < 4; ++i) {
            const int rb = row0 + wr * 64 + i * 16 + ((lane >> 4) << 2);
            #pragma unroll
            for (int j = 0; j < 4; ++j) {
                const int cc = col0 + wc * 64 + j * 16 + lr16;
                #pragma unroll
                for (int r = 0; r < 4; ++r) {
                    const int row = rb + r;
                    zbf[((size_t)m * 4096 + row) * 1024 + (cc - 1024)] =
                        __float2bfloat16(acc[i][j][r]);
                }
            }
        }
    }
    #undef STAGE
    #undef COMPUTE
}

// ---------------------------------------------------------------------------
// K3: xproj as bf16 MFMA GEMM. A = xcbf [3][4096][1024] (row remap for rev),
// B = xwbf [6][64][1024]. C = xd fp32 [6][4096][64]. Tile 128x64, BK=32.
// ---------------------------------------------------------------------------
__global__ __launch_bounds__(256) void k_xproj(
    const unsigned short* __restrict__ xcbf,
    const unsigned short* __restrict__ xwbf,
    float* __restrict__ xd)
{
    const int s = blockIdx.z;
    const int m = (s >= 3) ? (s - 3) : s;
    const bool rev = s >= 3;
    const unsigned short* __restrict__ A = xcbf + (size_t)m * 4096 * 1024;
    const unsigned short* __restrict__ Bw = xwbf + (size_t)s * 64 * 1024;
    const int row0 = blockIdx.x * 128;
    const int NT = 32;  // K=1024 / 32

    const int tid = threadIdx.x;
    const int lane = tid & 63;
    const int wave = tid >> 6;
    const int wr = wave >> 1, wc = wave & 1;
    const int lr16 = lane & 15;
    const int kk8 = (lane >> 4) << 3;

    __shared__ __align__(16) short sA[2][128 * 32];
    __shared__ __align__(16) short sB[2][64 * 32];

    f32x4 acc[4][2];
    #pragma unroll
    for (int i = 0; i < 4; ++i)
        #pragma unroll
        for (int j = 0; j < 2; ++j)
            acc[i][j] = (f32x4){0.f, 0.f, 0.f, 0.f};

    #define STAGEX(buf, t)                                                       \
        {                                                                        \
            const int k0 = (t) * 32;                                             \
            _Pragma("unroll")                                                    \
            for (int i = 0; i < 2; ++i) {                                        \
                const int c = i * 256 + tid;                                     \
                const int rowc = c >> 2;                                         \
                const int kc = (c & 3) << 3;                                     \
                const int arow = row0 + rowc;                                    \
                const int ab = arow >> 7, at = arow & 127;                       \
                const int srow = ab * NN + (rev ? (NN - 1 - at) : at);           \
                gload16(A + (size_t)srow * 1024 + k0 + kc,                       \
                        &sA[buf][rowc * 32 + kc]);                               \
            }                                                                    \
            {                                                                    \
                const int rowc = tid >> 2;                                       \
                const int kc = (tid & 3) << 3;                                   \
                gload16(Bw + (size_t)rowc * 1024 + k0 + kc,                      \
                        &sB[buf][rowc * 32 + kc]);                               \
            }                                                                    \
        }

    #define COMPUTEX(buf)                                                        \
        {                                                                        \
            bf16x8 af[4], bfr[2];                                                \
            _Pragma("unroll")                                                    \
            for (int i = 0; i < 4; ++i)                                          \
                af[i] = *(const bf16x8*)&sA[buf][(wr * 64 + i * 16 + lr16) * 32 + kk8]; \
            _Pragma("unroll")                                                    \
            for (int j = 0; j < 2; ++j)                                          \
                bfr[j] = *(const bf16x8*)&sB[buf][(wc * 32 + j * 16 + lr16) * 32 + kk8]; \
            _Pragma("unroll")                                                    \
            for (int i = 0; i < 4; ++i)                                          \
                _Pragma("unroll")                                                \
                for (int j = 0; j < 2; ++j)                                      \
                    acc[i][j] = __builtin_amdgcn_mfma_f32_16x16x32_bf16(         \
                        af[i], bfr[j], acc[i][j], 0, 0, 0);                      \
        }

    STAGEX(0, 0);
    __syncthreads();
    int cur = 0;
    for (int t = 0; t < NT - 1; ++t) {
        STAGEX(cur ^ 1, t + 1);
        COMPUTEX(cur);
        __syncthreads();
        cur ^= 1;
    }
    COMPUTEX(cur);

    #pragma unroll
    for (int i = 0; i < 4; ++i) {
        const int rb = row0 + wr * 64 + i * 16 + ((lane >> 4) << 2);
        #pragma unroll
        for (int j = 0; j < 2; ++j) {
            const int cc = wc * 32 + j * 16 + lr16;
            #pragma unroll
            for (int r = 0; r < 4; ++r) {
                const int row = rb + r;
                xd[((size_t)s * 4096 + row) * 64 + cc] = acc[i][j][r];
            }
        }
    }
    #undef STAGEX
    #undef COMPUTEX
}

// ---------------------------------------------------------------------------
// K3b: delta precompute, TRANSPOSED f16 output [s,b,d,t] so the scan can
// load 8 steps per 16B. Softplus via raw v_exp/v_log.
// ---------------------------------------------------------------------------
__global__ __launch_bounds__(256) void k_delta(
    const float* __restrict__ xd, const float* __restrict__ dtw,
    const float* __restrict__ dtb, unsigned short* __restrict__ deltaT)
{
    const int s = blockIdx.z, b = blockIdx.y;
    const int d = blockIdx.x * 256 + threadIdx.x;

    float wdt[NDR];
    const float* __restrict__ wp = dtw + ((size_t)s * NDI + d) * NDR;
    #pragma unroll
    for (int r = 0; r < NDR; r += 4)
        *(float4*)&wdt[r] = *(const float4*)(wp + r);
    const float bias = dtb[s * NDI + d];

    const float* __restrict__ xrow = xd + ((size_t)(s * NB + b)) * NN * 64;
    unsigned short* __restrict__ dout =
        deltaT + (((size_t)(s * NB + b)) * NDI + d) * NN;

    for (int t8 = 0; t8 < NN / 8; ++t8) {
        ushort4 o0, o1;
        unsigned short* op0 = (unsigned short*)&o0;
        unsigned short* op1 = (unsigned short*)&o1;
        #pragma unroll
        for (int k = 0; k < 8; ++k) {
            const int t = t8 * 8 + k;
            const float* __restrict__ xr = xrow + (size_t)t * 64;  // uniform
            float dl = bias;
            #pragma unroll
            for (int q = 0; q < 8; ++q) {
                const float4 v = *(const float4*)(xr + q * 4);
                dl = fmaf(v.x, wdt[q * 4 + 0], dl);
                dl = fmaf(v.y, wdt[q * 4 + 1], dl);
                dl = fmaf(v.z, wdt[q * 4 + 2], dl);
                dl = fmaf(v.w, wdt[q * 4 + 3], dl);
            }
            // stable softplus: max(x,0) + ln(1 + 2^(-|x|*L2E))
            const float e = EXP2(-fabsf(dl) * L2E);
            const float dlt = fmaxf(dl, 0.f) + LOG2(1.f + e) * LN2;
            if (k < 4) op0[k] = f2hf(dlt);
            else       op1[k - 4] = f2hf(dlt);
        }
        *(ushort4*)(dout + t8 * 8) = o0;
        *(ushort4*)(dout + t8 * 8 + 4) = o1;
    }
}

// ---------------------------------------------------------------------------
// K4: selective scan v7: state-split lane pairs + software pipeline +
// raw v_exp_f32 transcendentals. y6 output now bf16 (halved write traffic).
// ---------------------------------------------------------------------------
__global__ __launch_bounds__(256) void k_scan(
    const unsigned short* __restrict__ xcbf, const float* __restrict__ xd,
    const unsigned short* __restrict__ deltaT,
    const float* __restrict__ alog, const float* __restrict__ Dp,
    unsigned short* __restrict__ y6)
{
    const int s = blockIdx.z, b = blockIdx.y;
    const int tid = threadIdx.x;
    const int jg = tid & 1;                       // state half
    const int d = blockIdx.x * 128 + (tid >> 1);  // channel
    const int m = (s >= 3) ? (s - 3) : s;
    const bool rev = s >= 3;

    float a2[8], h[8];
    const float* __restrict__ ap = alog + ((size_t)s * NDI + d) * NDS + jg * 8;
    #pragma unroll
    for (int j = 0; j < 8; j += 4) {
        const float4 v = *(const float4*)(ap + j);
        // a2 = -exp(A_log)*log2(e) = -exp2(A_log*L2E)*L2E
        a2[j]     = -EXP2(v.x * L2E) * L2E;
        a2[j + 1] = -EXP2(v.y * L2E) * L2E;
        a2[j + 2] = -EXP2(v.z * L2E) * L2E;
        a2[j + 3] = -EXP2(v.w * L2E) * L2E;
        h[j] = h[j + 1] = h[j + 2] = h[j + 3] = 0.f;
    }
    const float Dd = Dp[s * NDI + d];

    const unsigned short* __restrict__ up =
        xcbf + ((size_t)(m * NB + b)) * NN * NDI + d;
    const float* __restrict__ xr =
        xd + ((size_t)(s * NB + b)) * NN * 64 + 32 + jg * 8;
    const unsigned short* __restrict__ dpT =
        deltaT + (((size_t)(s * NB + b)) * NDI + d) * NN;
    unsigned short* __restrict__ yp =
        y6 + ((size_t)(s * NB + b)) * NN * NDI + d;

    int un = (rev ? (NN - 1) : 0) * NDI;
    const int ustep = rev ? -NDI : NDI;
    const bool writer = (jg == 0);

    // prologue: t=0 inputs + first two delta groups
    uint4 dv  = *(const uint4*)dpT;
    uint4 dvn = *(const uint4*)(dpT + 8);
    float u = bf2f(up[un]); un += ustep;
    float4 B0 = *(const float4*)(xr);
    float4 B1 = *(const float4*)(xr + 4);
    float4 C0 = *(const float4*)(xr + 16);
    float4 C1 = *(const float4*)(xr + 20);

    for (int t8 = 0; t8 < NN / 8; ++t8) {
        #pragma unroll
        for (int k = 0; k < 8; ++k) {
            // prefetch step t+1 (reads ≤256B past slab end on final step; ws-safe)
            const float* __restrict__ xn = xr + 64;
            const float4 nB0 = *(const float4*)(xn);
            const float4 nB1 = *(const float4*)(xn + 4);
            const float4 nC0 = *(const float4*)(xn + 16);
            const float4 nC1 = *(const float4*)(xn + 20);
            const float u_n = bf2f(up[un]); un += ustep;

            const float delta = hf2f(((const unsigned short*)&dv)[k]);
            const float du = delta * u;
            float y = 0.f;
            #pragma unroll
            for (int j = 0; j < 4; ++j) {
                const float dA = EXP2(delta * a2[j]);
                h[j] = fmaf(dA, h[j], du * ((const float*)&B0)[j]);
                y = fmaf(h[j], ((const float*)&C0)[j], y);
            }
            #pragma unroll
            for (int j = 0; j < 4; ++j) {
                const float dA = EXP2(delta * a2[4 + j]);
                h[4 + j] = fmaf(dA, h[4 + j], du * ((const float*)&B1)[j]);
                y = fmaf(h[4 + j], ((const float*)&C1)[j], y);
            }
            y = pair_sum(y);
            if (writer) yp[(size_t)(t8 * 8 + k) * NDI] = f2bf(fmaf(u, Dd, y));

            u = u_n; B0 = nB0; B1 = nB1; C0 = nC0; C1 = nC1; xr = xn;
        }
        dv = dvn;
        dvn = *(const uint4*)(dpT + (t8 + 2) * 8);  // reads past only at the tail; ws-safe
    }
}

// ---------------------------------------------------------------------------
// K5: LN + fwd/rev combine + SiLU(z) gating. y6 input bf16.
// ---------------------------------------------------------------------------
__global__ __launch_bounds__(256) void k_combine(
    const unsigned short* __restrict__ y6, const __hip_bfloat16* __restrict__ zbf,
    const float* __restrict__ g, const float* __restrict__ be,
    __hip_bfloat16* __restrict__ yg)
{
    const int t = blockIdx.x, b = blockIdx.y, m = blockIdx.z;
    const int tid = threadIdx.x;
    const int dd = tid << 2;
    const unsigned short* __restrict__ rowf =
        y6 + ((size_t)(m * NB + b) * NN + t) * NDI;
    const unsigned short* __restrict__ rowr =
        y6 + ((size_t)((m + 3) * NB + b) * NN + (NN - 1 - t)) * NDI;
    const __hip_bfloat16* __restrict__ zrow =
        zbf + ((size_t)(m * NB + b) * NN + t) * NDI;

    const ushort4 vfu = *(const ushort4*)(rowf + dd);
    const ushort4 vru = *(const ushort4*)(rowr + dd);
    float vf[4], vr2[4];
    vf[0] = bf2f(vfu.x); vf[1] = bf2f(vfu.y); vf[2] = bf2f(vfu.z); vf[3] = bf2f(vfu.w);
    vr2[0] = bf2f(vru.x); vr2[1] = bf2f(vru.y); vr2[2] = bf2f(vru.z); vr2[3] = bf2f(vru.w);

    float sf = 0.f, qf = 0.f, sr = 0.f, qr = 0.f;
    #pragma unroll
    for (int q = 0; q < 4; ++q) {
        sf += vf[q]; qf = fmaf(vf[q], vf[q], qf);
        sr += vr2[q]; qr = fmaf(vr2[q], vr2[q], qr);
    }

    #pragma unroll
    for (int off = 32; off > 0; off >>= 1) {
        sf += __shfl_down(sf, off, 64);
        qf += __shfl_down(qf, off, 64);
        sr += __shfl_down(sr, off, 64);
        qr += __shfl_down(qr, off, 64);
    }
    __shared__ float red[4][4];
    const int wv = tid >> 6;
    if ((tid & 63) == 0) { red[wv][0] = sf; red[wv][1] = qf; red[wv][2] = sr; red[wv][3] = qr; }
    __syncthreads();
    const float tsf = red[0][0] + red[1][0] + red[2][0] + red[3][0];
    const float tqf = red[0][1] + red[1][1] + red[2][1] + red[3][1];
    const float tsr = red[0][2] + red[1][2] + red[2][2] + red[3][2];
    const float tqr = red[0][3] + red[1][3] + red[2][3] + red[3][3];
    const float muf = tsf * (1.f / NDI);
    const float varf = tqf * (1.f / NDI) - muf * muf;
    const float rsf = rsqrtf(varf + 1e-5f);
    const float mur = tsr * (1.f / NDI);
    const float varr = tqr * (1.f / NDI) - mur * mur;
    const float rsr = rsqrtf(varr + 1e-5f);

    const float4 gf = *(const float4*)(g + m * NDI + dd);
    const float4 bf = *(const float4*)(be + m * NDI + dd);
    const float4 gr = *(const float4*)(g + (m + 3) * NDI + dd);
    const float4 br = *(const float4*)(be + (m + 3) * NDI + dd);
    const ushort4 zu = *(const ushort4*)(zrow + dd);

    float lf[4], lr2[4], zv[4];
    lf[0] = (vf[0] - muf) * rsf * gf.x + bf.x;
    lf[1] = (vf[1] - muf) * rsf * gf.y + bf.y;
    lf[2] = (vf[2] - muf) * rsf * gf.z + bf.z;
    lf[3] = (vf[3] - muf) * rsf * gf.w + bf.w;
    lr2[0] = (vr2[0] - mur) * rsr * gr.x + br.x;
    lr2[1] = (vr2[1] - mur) * rsr * gr.y + br.y;
    lr2[2] = (vr2[2] - mur) * rsr * gr.z + br.z;
    lr2[3] = (vr2[3] - mur) * rsr * gr.w + br.w;
    zv[0] = bf2f(zu.x);
    zv[1] = bf2f(zu.y);
    zv[2] = bf2f(zu.z);
    zv[3] = bf2f(zu.w);

    ushort4 o;
    unsigned short* op = (unsigned short*)&o;
    #pragma unroll
    for (int q = 0; q < 4; ++q) {
        op[q] = f2bf((lf[q] + lr2[q]) * zv[q] * sigm(zv[q]));
    }
    *(ushort4*)(yg + ((size_t)(m * NB + b) * NN + t) * NDI + dd) = o;
}

// ---------------------------------------------------------------------------
// K6: out_proj as bf16 MFMA GEMM + fp32 residual add.
// ---------------------------------------------------------------------------
__global__ __launch_bounds__(256) void k_gemm_outproj(
    const unsigned short* __restrict__ Abf,
    const unsigned short* __restrict__ Wbf,
    const float* __restrict__ rr, const float* __restrict__ nn,
    const float* __restrict__ tt, float* __restrict__ out)
{
    const int row0 = blockIdx.x * 128;   // over 12288
    const int col0 = blockIdx.y * 128;   // over 512
    const int K = 1024;
    const int NT = K / 32;

    const int tid = threadIdx.x;
    const int lane = tid & 63;
    const int wave = tid >> 6;
    const int wr = wave >> 1, wc = wave & 1;
    const int lr16 = lane & 15;
    const int kk8 = (lane >> 4) << 3;

    __shared__ __align__(16) short sA[2][128 * 32];
    __shared__ __align__(16) short sB[2][128 * 32];

    f32x4 acc[4][4];
    #pragma unroll
    for (int i = 0; i < 4; ++i)
        #pragma unroll
        for (int j = 0; j < 4; ++j)
            acc[i][j] = (f32x4){0.f, 0.f, 0.f, 0.f};

    #define STAGE(buf, t)                                                        \
        {                                                                        \
            const int k0 = (t) * 32;                                             \
            _Pragma("unroll")                                                    \
            for (int i = 0; i < 2; ++i) {                                        \
                const int c = i * 256 + tid;                                     \
                const int rowc = c >> 2;                                         \
                const int kc = (c & 3) << 3;                                     \
                gload16(Abf + (size_t)(row0 + rowc) * K + k0 + kc,               \
                        &sA[buf][rowc * 32 + kc]);                               \
                gload16(Wbf + (size_t)(col0 + rowc) * K + k0 + kc,               \
                        &sB[buf][rowc * 32 + kc]);                               \
            }                                                                    \
        }

    #define COMPUTE(buf)                                                         \
        {                                                                        \
            bf16x8 af[4], bfr[4];                                                \
            _Pragma("unroll")                                                    \
            for (int i = 0; i < 4; ++i) {                                        \
                af[i]  = *(const bf16x8*)&sA[buf][(wr * 64 + i * 16 + lr16) * 32 + kk8]; \
                bfr[i] = *(const bf16x8*)&sB[buf][(wc * 64 + i * 16 + lr16) * 32 + kk8]; \
            }                                                                    \
            _Pragma("unroll")                                                    \
            for (int i = 0; i < 4; ++i)                                          \
                _Pragma("unroll")                                                \
                for (int j = 0; j < 4; ++j)                                      \
                    acc[i][j] = __builtin_amdgcn_mfma_f32_16x16x32_bf16(         \
                        af[i], bfr[j], acc[i][j], 0, 0, 0);                      \
        }

    STAGE(0, 0);
    __syncthreads();
    int cur = 0;
    for (int t = 0; t < NT - 1; ++t) {
        STAGE(cur ^ 1, t + 1);
        COMPUTE(cur);
        __syncthreads();
        cur ^= 1;
    }
    COMPUTE(cur);

    const int m = row0 >> 12;  // uniform per block (128 | 4096)
    const float* __restrict__ resid = (m == 0) ? rr : (m == 1) ? nn : tt;
    #pragma unroll
    for (int i = 0; i < 4; ++i) {
        const int rb = row0 + wr * 64 + i * 16 + ((lane >> 4) << 2);
        #pragma unroll
        for (int j = 0; j < 4; ++j) {
            const int cc = col0 + wc * 64 + j * 16 + lr16;
            #pragma unroll
            for (int r = 0; r < 4; ++r) {
                const int row = rb + r;
                const int bt = row & 4095;
                out[(size_t)row * ND + cc] =
                    acc[i][j][r] + resid[(size_t)bt * ND + cc];
            }
        }
    }
    #undef STAGE
    #undef COMPUTE
}

// ---------------------------------------------------------------------------
extern "C" void kernel_launch(void* const* d_in, const int* in_sizes, int n_in,
                              void* d_out, int out_size, void* d_ws, size_t ws_size,
                              hipStream_t stream) {
    const float* rr   = (const float*)d_in[0];
    const float* nn   = (const float*)d_in[1];
    const float* tt   = (const float*)d_in[2];
    const float* wip  = (const float*)d_in[3];   // (3,2048,512)
    const float* cw   = (const float*)d_in[4];   // (3,1024,1,3,3)
    const float* cb   = (const float*)d_in[5];
    const float* gm   = (const float*)d_in[6];
    const float* bt   = (const float*)d_in[7];
    const float* mn   = (const float*)d_in[8];
    const float* vr   = (const float*)d_in[9];
    const float* xw   = (const float*)d_in[10];  // (6,64,1024)
    const float* dtw  = (const float*)d_in[11];  // (6,1024,32)
    const float* dtb  = (const float*)d_in[12];
    const float* alog = (const float*)d_in[13];  // (6,1024,16)
    const float* Dp   = (const float*)d_in[14];
    const float* lng  = (const float*)d_in[15];
    const float* lnb  = (const float*)d_in[16];
    const float* wout = (const float*)d_in[17];  // (512,1024)
    float* out = (float*)d_out;

    // workspace layout (bytes), total ~203 MiB
    uint8_t* p = (uint8_t*)d_ws;
    unsigned short* Abf    = (unsigned short*)p;  p += (size_t)3 * 4096 * 512 * 2;   // 12.6 MB
    unsigned short* Wbf    = (unsigned short*)p;  p += (size_t)3 * 2048 * 512 * 2;   //  6.3 MB
    unsigned short* Woutbf = (unsigned short*)p;  p += (size_t)512 * 1024 * 2;       //  1.0 MB
    unsigned short* Xwbf   = (unsigned short*)p;  p += (size_t)6 * 64 * 1024 * 2;    //  0.8 MB
    __hip_bfloat16* zbf    = (__hip_bfloat16*)p;  p += (size_t)3 * 4096 * 1024 * 2;  // 25.2 MB
    unsigned short* xcbf   = (unsigned short*)p;  p += (size_t)3 * 4096 * 1024 * 2;  // 25.2 MB
    float*          xdb    = (float*)p;           p += (size_t)6 * 4096 * 64 * 4;    //  6.3 MB
    unsigned short* y6bf   = (unsigned short*)p;  p += (size_t)6 * 4096 * 1024 * 2;  // 50.3 MB
    unsigned short* deltaT = (unsigned short*)p;  p += (size_t)6 * 4096 * 1024 * 2;  // 50.3 MB
    __hip_bfloat16* ygbf   = (__hip_bfloat16*)p;  p += (size_t)3 * 4096 * 1024 * 2;  // 25.2 MB

    // bf16 conversions
    k_cvt3<<<dim3(2048, 1, 3), 256, 0, stream>>>(rr, nn, tt, Abf, 4096 * 512 / 4);
    k_cvt<<<dim3(2048), 256, 0, stream>>>(wip,  Wbf, 3 * 2048 * 512 / 4);
    k_cvt<<<dim3(512),  256, 0, stream>>>(wout, Woutbf, 512 * 1024 / 4);
    k_cvt<<<dim3(384),  256, 0, stream>>>(xw,   Xwbf, 6 * 64 * 1024 / 4);

    k_gemm_inproj_conv<<<dim3(32, 16, 3), 256, 0, stream>>>(
        Abf, Wbf, cw, cb, gm, bt, mn, vr, xcbf, zbf);
    k_xproj<<<dim3(32, 1, 6), 256, 0, stream>>>(xcbf, Xwbf, xdb);
    k_delta<<<dim3(4, 32, 6), 256, 0, stream>>>(xdb, dtw, dtb, deltaT);
    k_scan<<<dim3(8, 32, 6), 256, 0, stream>>>(xcbf, xdb, deltaT, alog, Dp, y6bf);
    k_combine<<<dim3(128, 32, 3), 256, 0, stream>>>(y6bf, zbf, lng, lnb, ygbf);
    k_gemm_outproj<<<dim3(96, 4, 1), 256, 0, stream>>>(
        (const unsigned short*)ygbf, Woutbf, rr, nn, tt, out);
}